// Round 2
// baseline (2576.125 us; speedup 1.0000x reference)
//
#include <hip/hip_runtime.h>
#include <float.h>

#define N 4096
#define FI 44
#define RK 11
#define KNN 16
#define NSEL 25   // K + 9 ranks kept
#define NROW 4    // rows per block in dist/topk
#define NPB 4     // nodes per block in edge kernel
#define EPB 64    // edges per block (NPB * KNN)
#define EPV 4     // edges per thread in edge kernel

// ---------------- K1: squared row norms ----------------
__global__ void k_sqnorm(const float* __restrict__ h, float* __restrict__ sq) {
  int i = blockIdx.x * blockDim.x + threadIdx.x;
  if (i < N) {
    const float4* hr = reinterpret_cast<const float4*>(h + (size_t)i * FI);
    float s = 0.f;
#pragma unroll
    for (int c = 0; c < FI / 4; c++) { float4 v = hr[c]; s += v.x*v.x + v.y*v.y + v.z*v.z + v.w*v.w; }
    sq[i] = s;
  }
}

// ---------------- K2: distance rows + top-25 selection ----------------
// Keys are monotonic-mapped u32 so (value,index) packs into a single u64:
// key = (mapped << 12) | j. Min over u64 == lexicographic (value, index) min,
// matching jax.lax.top_k stable tie-breaking.
__global__ __launch_bounds__(256) void k_dist_topk(const float* __restrict__ h,
                                                   const float* __restrict__ sq,
                                                   const float* __restrict__ mask,
                                                   int* __restrict__ ctr_idx,
                                                   int* __restrict__ nbr_idx) {
  __shared__ __align__(16) unsigned int drow[NROW][N];   // 64 KB of mapped keys
  __shared__ __align__(16) float hi[NROW][FI];
  __shared__ float sqi[NROW];
  const int tid = threadIdx.x;
  const int r0 = blockIdx.x * NROW;

  for (int t = tid; t < NROW * FI; t += 256) hi[t / FI][t % FI] = h[(size_t)(r0 + t / FI) * FI + (t % FI)];
  if (tid < NROW) sqi[tid] = sq[r0 + tid];
  __syncthreads();

  for (int s = 0; s < N / 256; s++) {
    int j = s * 256 + tid;
    const float4* hj = reinterpret_cast<const float4*>(h + (size_t)j * FI);
    float4 a[FI / 4];
#pragma unroll
    for (int c = 0; c < FI / 4; c++) a[c] = hj[c];
    float sqj = sq[j];
#pragma unroll
    for (int rr = 0; rr < NROW; rr++) {
      const float4* hir = reinterpret_cast<const float4*>(&hi[rr][0]);
      float dot = 0.f;
#pragma unroll
      for (int c = 0; c < FI / 4; c++) {
        float4 b = hir[c];
        dot += a[c].x*b.x + a[c].y*b.y + a[c].z*b.z + a[c].w*b.w;
      }
      int row = r0 + rr;
      float D = fabsf(sqi[rr] + sqj - 2.f * dot) * mask[(size_t)row * N + j];
      if (j == row) D -= 2.f;
      unsigned int u = __float_as_uint(D);
      u ^= (unsigned int)((int)u >> 31) | 0x80000000u;   // monotonic map
      drow[rr][j] = u;
    }
  }
  __syncthreads();

  // wave w selects for row w. Lane owns 64 contiguous-in-chunks cols:
  // j = 4*lane + 256*t + i  (16 x ds_read_b128, bank-uniform).
  const int w = tid >> 6, lane = tid & 63;
  unsigned int* dr = drow[w];
  unsigned long long cand;

  auto rescan = [&]() {
    // 4 independent compare chains (one per uint4 component), then lex merge.
    unsigned int bvx = 0xFFFFFFFFu, bvy = 0xFFFFFFFFu, bvz = 0xFFFFFFFFu, bvw = 0xFFFFFFFFu;
    int bjx = 0, bjy = 0, bjz = 0, bjw = 0;
#pragma unroll
    for (int t = 0; t < 16; t++) {
      uint4 v4 = *reinterpret_cast<const uint4*>(dr + 4 * (lane + 64 * t));
      int j0 = 4 * lane + 256 * t;
      if (v4.x < bvx) { bvx = v4.x; bjx = j0; }
      if (v4.y < bvy) { bvy = v4.y; bjy = j0 + 1; }
      if (v4.z < bvz) { bvz = v4.z; bjz = j0 + 2; }
      if (v4.w < bvw) { bvw = v4.w; bjw = j0 + 3; }
    }
    // lex merges (value, then smaller j)
    if (bvy < bvx || (bvy == bvx && bjy < bjx)) { bvx = bvy; bjx = bjy; }
    if (bvw < bvz || (bvw == bvz && bjw < bjz)) { bvz = bvw; bjz = bjw; }
    if (bvz < bvx || (bvz == bvx && bjz < bjx)) { bvx = bvz; bjx = bjz; }
    cand = ((unsigned long long)bvx << 12) | (unsigned long long)bjx;
  };

  rescan();

  for (int it = 0; it < NSEL; it++) {
    unsigned long long k = cand;
#pragma unroll
    for (int off = 1; off < 64; off <<= 1) {
      unsigned long long o = __shfl_xor(k, off, 64);
      if (o < k) k = o;
    }
    int wj = (int)(k & 4095u);
    if (lane == 0) {
      int row = r0 + w;
      if (it == 0) ctr_idx[row] = wj;
      else if (it >= 9) nbr_idx[row * KNN + (it - 9)] = wj;
    }
    if (((wj >> 2) & 63) == lane) {   // owner invalidates + rescans (fast path)
      dr[wj] = 0xFFFFFFFFu;
      rescan();
    }
  }
}

// ---------------- K3: fused edge-conditioned conv ----------------
// 256 threads = 16 q (f-lanes) x 16 pp (edge slots); each thread handles 4
// edges (one per node k). Weights transposed into LDS in r-halves (46 KB)
// so total LDS ~73 KB -> 2 blocks/CU. Staging: coalesced gather-4 global +
// ds_write_b128 (bank-uniform).
__global__ __launch_bounds__(256, 2) void k_edge(
    const float* __restrict__ h,
    const int* __restrict__ ctr_idx, const int* __restrict__ nbr_idx,
    const float* __restrict__ W_lab, const float* __restrict__ b_lab,
    const float* __restrict__ W1, const float* __restrict__ b1,
    const float* __restrict__ W2, const float* __restrict__ b2,
    const float* __restrict__ Wl, const float* __restrict__ bl,
    float* __restrict__ out)
{
  __shared__ __align__(16) float WT[264 * FI];   // 46.4 KB: one r-half of W1/W2 (or W_labT)
  __shared__ __align__(16) float x1s[EPB][FI];   // neighbor features
  __shared__ __align__(16) float lbs[EPB][FI];   // labels, then lab
  __shared__ __align__(16) float hcs[NPB][FI];   // center features
  __shared__ float tfs[EPB][RK];                 // t (then t * thetal)
  __shared__ float oacc[NPB][FI];                // output accumulator

  const int tid = threadIdx.x;
  const int b = blockIdx.x;
  const int q = tid & 15;        // f-lane
  const int pp = tid >> 4;       // edge slot within node

  // stage a transposed row-block [n0, n0+nh) of W (layout [44][ldw]) into WT[nl*44+c]
  auto stageW = [&](const float* __restrict__ W, int ldw, int n0, int nh) {
    for (int task = tid; task < nh * 11; task += 256) {
      int nl = task % nh, cc = task / nh;
      int n = n0 + nl;
      float4 wv;
      wv.x = W[(size_t)(4 * cc + 0) * ldw + n];
      wv.y = W[(size_t)(4 * cc + 1) * ldw + n];
      wv.z = W[(size_t)(4 * cc + 2) * ldw + n];
      wv.w = W[(size_t)(4 * cc + 3) * ldw + n];
      *reinterpret_cast<float4*>(&WT[nl * FI + 4 * cc]) = wv;
    }
  };

  // ---- gather ----
  for (int t = tid; t < NPB * FI; t += 256) oacc[t / FI][t % FI] = 0.f;
  for (int t = tid; t < NPB * FI; t += 256) {
    int nn = t / FI, c = t % FI;
    hcs[nn][c] = h[(size_t)ctr_idx[b * NPB + nn] * FI + c];
  }
  for (int t = tid; t < EPB * FI; t += 256) {
    int e = t / FI, c = t % FI;
    int nb = nbr_idx[(b * NPB + (e >> 4)) * KNN + (e & 15)];
    x1s[e][c] = h[(size_t)nb * FI + c];
  }
  __syncthreads();
  for (int t = tid; t < EPB * FI; t += 256) {
    int e = t / FI, c = t % FI;
    lbs[e][c] = x1s[e][c] - hcs[e >> 4][c];
  }
  __syncthreads();
  stageW(W_lab, FI, 0, FI);      // W_labT
  __syncthreads();

  // ---- P1: lab = leaky_relu(labels @ W_lab + b_lab); dls = ||labels||^2 ----
  float la[EPV][3];
  float dl[EPV];
#pragma unroll
  for (int k = 0; k < EPV; k++) {
    const float4* L = reinterpret_cast<const float4*>(&lbs[pp + 16 * k][0]);
    float s = 0.f;
#pragma unroll
    for (int cc = 0; cc < 11; cc++) { float4 v = L[cc]; s += v.x*v.x + v.y*v.y + v.z*v.z + v.w*v.w; }
    dl[k] = s;
  }
#pragma unroll
  for (int m = 0; m < 3; m++) {
    int f = q + 16 * m;
    if (f < FI) {
      float bb = b_lab[f];
      float th[EPV];
#pragma unroll
      for (int k = 0; k < EPV; k++) th[k] = bb;
      const float4* Wn = reinterpret_cast<const float4*>(&WT[f * FI]);
#pragma unroll
      for (int cc = 0; cc < 11; cc++) {
        float4 w4 = Wn[cc];
#pragma unroll
        for (int k = 0; k < EPV; k++) {
          float4 l4 = *reinterpret_cast<const float4*>(&lbs[pp + 16 * k][4 * cc]);
          th[k] += w4.x*l4.x + w4.y*l4.y + w4.z*l4.z + w4.w*l4.w;
        }
      }
#pragma unroll
      for (int k = 0; k < EPV; k++) la[k][m] = th[k] >= 0.f ? th[k] : 0.2f * th[k];
    }
  }
  // x1 f-slices (x1s is never overwritten)
  float xsl[EPV][3];
#pragma unroll
  for (int m = 0; m < 3; m++) {
    int f = q + 16 * m;
    if (f < FI)
#pragma unroll
      for (int k = 0; k < EPV; k++) xsl[k][m] = x1s[pp + 16 * k][f];
  }
  __syncthreads();                 // all lbs reads done
#pragma unroll
  for (int m = 0; m < 3; m++) {
    int f = q + 16 * m;
    if (f < FI)
#pragma unroll
      for (int k = 0; k < EPV; k++) lbs[pp + 16 * k][f] = la[k][m];
  }
  __syncthreads();                 // lab ready; WT free

  // load full lab rows into registers (176 VGPRs) + stage W1 first half
  float4 lab[EPV][11];
#pragma unroll
  for (int k = 0; k < EPV; k++)
#pragma unroll
    for (int cc = 0; cc < 11; cc++)
      lab[k][cc] = *reinterpret_cast<const float4*>(&lbs[pp + 16 * k][4 * cc]);
  stageW(W1, 484, 0, 264);
  __syncthreads();

  // ---- P2: t[e][r] = sum_f (b1 + lab@W1)[r,f] * x1[e,f], in two r-halves ----
  auto p2half = [&](int r0h, int rh) {
    for (int rl = 0; rl < rh; rl++) {
      int r = r0h + rl;
      float tp[EPV] = {0.f, 0.f, 0.f, 0.f};
#pragma unroll
      for (int m = 0; m < 3; m++) {
        int f = q + 16 * m;
        if (f < FI) {
          float bb = b1[r * FI + f];
          float th[EPV];
#pragma unroll
          for (int k = 0; k < EPV; k++) th[k] = bb;
          const float4* Wn = reinterpret_cast<const float4*>(&WT[(rl * FI + f) * 11 * 0 + (rl * FI + f) * FI]);
#pragma unroll
          for (int cc = 0; cc < 11; cc++) {
            float4 w4 = Wn[cc];
#pragma unroll
            for (int k = 0; k < EPV; k++) {
              float4 l4 = lab[k][cc];
              th[k] += w4.x*l4.x + w4.y*l4.y + w4.z*l4.z + w4.w*l4.w;
            }
          }
#pragma unroll
          for (int k = 0; k < EPV; k++) tp[k] += th[k] * xsl[k][m];
        }
      }
#pragma unroll
      for (int off = 1; off < 16; off <<= 1)
#pragma unroll
        for (int k = 0; k < EPV; k++) tp[k] += __shfl_xor(tp[k], off, 64);
      if (q == 0) {
#pragma unroll
        for (int k = 0; k < EPV; k++) tfs[pp + 16 * k][r] = tp[k];
      }
    }
  };
  p2half(0, 6);
  __syncthreads();
  stageW(W1, 484, 264, 220);
  __syncthreads();
  p2half(6, 5);
  __syncthreads();

  // ---- P3: t *= (lab @ W_thl + b_thl)  (lane q handles r=q) + stage W2a ----
  if (q < RK) {
    float tl[EPV];
#pragma unroll
    for (int k = 0; k < EPV; k++) tl[k] = bl[q];
#pragma unroll
    for (int cc = 0; cc < 11; cc++) {
#pragma unroll
      for (int i = 0; i < 4; i++) {
        float wv = Wl[(4 * cc + i) * RK + q];
#pragma unroll
        for (int k = 0; k < EPV; k++) {
          float l = i == 0 ? lab[k][cc].x : i == 1 ? lab[k][cc].y : i == 2 ? lab[k][cc].z : lab[k][cc].w;
          tl[k] += l * wv;
        }
      }
    }
#pragma unroll
    for (int k = 0; k < EPV; k++) tfs[pp + 16 * k][q] *= tl[k];
  }
  stageW(W2, 484, 0, 264);
  __syncthreads();

  // ---- P4: x[e][f] = sum_r (b2 + lab@W2)[r,f] * t'[e][r], two r-halves ----
  float xo[EPV][3] = {{0,0,0},{0,0,0},{0,0,0},{0,0,0}};
  auto p4half = [&](int r0h, int rh) {
    for (int rl = 0; rl < rh; rl++) {
      int r = r0h + rl;
      float tv[EPV];
#pragma unroll
      for (int k = 0; k < EPV; k++) tv[k] = tfs[pp + 16 * k][r];
#pragma unroll
      for (int m = 0; m < 3; m++) {
        int f = q + 16 * m;
        if (f < FI) {
          float bb = b2[r * FI + f];
          float th[EPV];
#pragma unroll
          for (int k = 0; k < EPV; k++) th[k] = bb;
          const float4* Wn = reinterpret_cast<const float4*>(&WT[(rl * FI + f) * FI]);
#pragma unroll
          for (int cc = 0; cc < 11; cc++) {
            float4 w4 = Wn[cc];
#pragma unroll
            for (int k = 0; k < EPV; k++) {
              float4 l4 = lab[k][cc];
              th[k] += w4.x*l4.x + w4.y*l4.y + w4.z*l4.z + w4.w*l4.w;
            }
          }
#pragma unroll
          for (int k = 0; k < EPV; k++) xo[k][m] += th[k] * tv[k];
        }
      }
    }
  };
  p4half(0, 6);
  __syncthreads();
  stageW(W2, 484, 264, 220);
  __syncthreads();
  p4half(6, 5);

  // ---- epilogue: distance weight, reduce over pp within wave, atomic ----
  float wk[EPV];
#pragma unroll
  for (int k = 0; k < EPV; k++) wk[k] = expf(-dl[k] * 0.1f) * (1.0f / 16.0f);
  const int lane = tid & 63;
#pragma unroll
  for (int m = 0; m < 3; m++) {
    int f = q + 16 * m;
    if (f < FI) {
#pragma unroll
      for (int k = 0; k < EPV; k++) {
        float v = xo[k][m] * wk[k];
        v += __shfl_xor(v, 16, 64);
        v += __shfl_xor(v, 32, 64);
        if ((lane >> 4) == 0) atomicAdd(&oacc[k][f], v);
      }
    }
  }
  __syncthreads();
  for (int t = tid; t < NPB * FI; t += 256) {
    int nn = t / FI, c = t % FI;
    out[(size_t)(b * NPB + nn) * FI + c] = oacc[nn][c];
  }
}

extern "C" void kernel_launch(void* const* d_in, const int* in_sizes, int n_in,
                              void* d_out, int out_size, void* d_ws, size_t ws_size,
                              hipStream_t stream) {
  const float* h     = (const float*)d_in[0];
  const float* mask  = (const float*)d_in[1];
  const float* W_lab = (const float*)d_in[2];
  const float* b_lab = (const float*)d_in[3];
  const float* W1    = (const float*)d_in[4];
  const float* b1    = (const float*)d_in[5];
  const float* W2    = (const float*)d_in[6];
  const float* b2    = (const float*)d_in[7];
  const float* Wl    = (const float*)d_in[8];
  const float* bl    = (const float*)d_in[9];

  float* sq = (float*)d_ws;
  int* ctr  = (int*)(sq + N);
  int* nbr  = ctr + N;

  k_sqnorm<<<N / 256, 256, 0, stream>>>(h, sq);
  k_dist_topk<<<N / NROW, 256, 0, stream>>>(h, sq, mask, ctr, nbr);
  k_edge<<<N / NPB, 256, 0, stream>>>(h, ctr, nbr, W_lab, b_lab, W1, b1, W2, b2, Wl, bl, (float*)d_out);
}

// Round 3
// 881.973 us; speedup vs baseline: 2.9209x; 2.9209x over previous
//
#include <hip/hip_runtime.h>
#include <float.h>

#define N 4096
#define FI 44
#define RK 11
#define KNN 16
#define NSEL 25   // K + 9 ranks kept
#define NROW 4    // rows per block in dist/topk
#define NPB 2     // nodes per block in edge kernel
#define EPB 32    // edges per block (NPB * KNN)

typedef unsigned long long u64;

// ---------------- K1: squared row norms ----------------
__global__ void k_sqnorm(const float* __restrict__ h, float* __restrict__ sq) {
  int i = blockIdx.x * blockDim.x + threadIdx.x;
  if (i < N) {
    const float4* hr = reinterpret_cast<const float4*>(h + (size_t)i * FI);
    float s = 0.f;
#pragma unroll
    for (int c = 0; c < FI / 4; c++) { float4 v = hr[c]; s += v.x*v.x + v.y*v.y + v.z*v.z + v.w*v.w; }
    sq[i] = s;
  }
}

// ---------------- K2: distance rows + top-25 via threshold + bitonic ----------------
// u64 key = (monotonic-mapped fp32 << 12) | col  => min == lexicographic
// (value, index) min, matching jax.lax.top_k tie-breaking.
__global__ __launch_bounds__(256) void k_dist_topk(const float* __restrict__ h,
                                                   const float* __restrict__ sq,
                                                   const float* __restrict__ mask,
                                                   int* __restrict__ ctr_idx,
                                                   int* __restrict__ nbr_idx) {
  __shared__ __align__(16) unsigned int drow[NROW][N];   // 64 KB mapped keys
  __shared__ __align__(16) float hi[NROW][FI];
  __shared__ float sqi[NROW];
  __shared__ u64 cbuf[NROW][128];
  __shared__ int cnts[NROW];
  const int tid = threadIdx.x;
  const int r0 = blockIdx.x * NROW;

  if (tid < NROW) cnts[tid] = 0;
  for (int t = tid; t < NROW * FI; t += 256) hi[t / FI][t % FI] = h[(size_t)(r0 + t / FI) * FI + (t % FI)];
  if (tid < NROW) sqi[tid] = sq[r0 + tid];
  __syncthreads();

  for (int s = 0; s < N / 256; s++) {
    int j = s * 256 + tid;
    const float4* hj = reinterpret_cast<const float4*>(h + (size_t)j * FI);
    float4 a[FI / 4];
#pragma unroll
    for (int c = 0; c < FI / 4; c++) a[c] = hj[c];
    float sqj = sq[j];
#pragma unroll
    for (int rr = 0; rr < NROW; rr++) {
      const float4* hir = reinterpret_cast<const float4*>(&hi[rr][0]);
      float dot = 0.f;
#pragma unroll
      for (int c = 0; c < FI / 4; c++) {
        float4 b = hir[c];
        dot += a[c].x*b.x + a[c].y*b.y + a[c].z*b.z + a[c].w*b.w;
      }
      int row = r0 + rr;
      float D = fabsf(sqi[rr] + sqj - 2.f * dot) * mask[(size_t)row * N + j];
      if (j == row) D -= 2.f;
      unsigned int u = __float_as_uint(D);
      u ^= (unsigned int)((int)u >> 31) | 0x80000000u;   // monotonic map
      drow[rr][j] = u;
    }
  }
  __syncthreads();

  const int w = tid >> 6, lane = tid & 63;
  unsigned int* dr = drow[w];
  const u64 UMAX = ~0ull;
  const int row = r0 + w;

  // ---- per-lane min over its 64 elems (j = 4*lane + 256*t + i) ----
  u64 lm = UMAX;
#pragma unroll
  for (int t = 0; t < 16; t++) {
    uint4 v4 = *reinterpret_cast<const uint4*>(dr + 4 * (lane + 64 * t));
    u64 j0 = (u64)(4 * lane + 256 * t);
    u64 k0 = ((u64)v4.x << 12) | j0;
    u64 k1 = ((u64)v4.y << 12) | (j0 + 1);
    u64 k2 = ((u64)v4.z << 12) | (j0 + 2);
    u64 k3 = ((u64)v4.w << 12) | (j0 + 3);
    u64 m01 = k0 < k1 ? k0 : k1;
    u64 m23 = k2 < k3 ? k2 : k3;
    u64 m = m01 < m23 ? m01 : m23;
    lm = m < lm ? m : lm;
  }

  auto bitonic64 = [&](u64 v) -> u64 {
#pragma unroll
    for (int kk = 2; kk <= 64; kk <<= 1) {
#pragma unroll
      for (int jj = kk >> 1; jj > 0; jj >>= 1) {
        u64 o = __shfl_xor(v, jj, 64);
        bool lower = (lane & jj) == 0;
        bool asc = (lane & kk) == 0;
        u64 mn = o < v ? o : v;
        u64 mx = o < v ? v : o;
        v = (lower == asc) ? mn : mx;
      }
    }
    return v;
  };

  // ---- T = 25th smallest lane-min: upper bound on the true 25th element ----
  u64 sv = bitonic64(lm);
  u64 T = __shfl(sv, 24, 64);

  // ---- compact all keys <= T (guaranteed >= 25 of them) ----
#pragma unroll
  for (int t = 0; t < 16; t++) {
    uint4 v4 = *reinterpret_cast<const uint4*>(dr + 4 * (lane + 64 * t));
    u64 j0 = (u64)(4 * lane + 256 * t);
    u64 kz0 = ((u64)v4.x << 12) | j0;
    u64 kz1 = ((u64)v4.y << 12) | (j0 + 1);
    u64 kz2 = ((u64)v4.z << 12) | (j0 + 2);
    u64 kz3 = ((u64)v4.w << 12) | (j0 + 3);
    if (kz0 <= T) { int p = atomicAdd(&cnts[w], 1); if (p < 128) cbuf[w][p] = kz0; }
    if (kz1 <= T) { int p = atomicAdd(&cnts[w], 1); if (p < 128) cbuf[w][p] = kz1; }
    if (kz2 <= T) { int p = atomicAdd(&cnts[w], 1); if (p < 128) cbuf[w][p] = kz2; }
    if (kz3 <= T) { int p = atomicAdd(&cnts[w], 1); if (p < 128) cbuf[w][p] = kz3; }
  }
  __syncthreads();

  int cnt = cnts[w];
  if (cnt <= 64) {
    // ---- one bitonic sort of the candidates gives ranks directly ----
    u64 cv = (lane < cnt) ? cbuf[w][lane] : UMAX;
    cv = bitonic64(cv);
    int idx = (int)(cv & 4095ull);
    if (lane == 0) ctr_idx[row] = idx;
    if (lane >= 9 && lane < NSEL) nbr_idx[row * KNN + (lane - 9)] = idx;
  } else {
    // ---- fallback: serial extraction (adversarial tie patterns only) ----
    u64 bkey;
    auto rescan = [&]() {
      u64 best = UMAX;
#pragma unroll
      for (int t = 0; t < 16; t++) {
        uint4 v4 = *reinterpret_cast<const uint4*>(dr + 4 * (lane + 64 * t));
        u64 j0 = (u64)(4 * lane + 256 * t);
        u64 k0 = ((u64)v4.x << 12) | j0;
        u64 k1 = ((u64)v4.y << 12) | (j0 + 1);
        u64 k2 = ((u64)v4.z << 12) | (j0 + 2);
        u64 k3 = ((u64)v4.w << 12) | (j0 + 3);
        k0 = k0 < k1 ? k0 : k1;
        k2 = k2 < k3 ? k2 : k3;
        k0 = k0 < k2 ? k0 : k2;
        best = k0 < best ? k0 : best;
      }
      bkey = best;
    };
    rescan();
    for (int it = 0; it < NSEL; it++) {
      u64 kk = bkey;
#pragma unroll
      for (int off = 1; off < 64; off <<= 1) {
        u64 o = __shfl_xor(kk, off, 64);
        if (o < kk) kk = o;
      }
      int wj = (int)(kk & 4095ull);
      if (lane == 0) {
        if (it == 0) ctr_idx[row] = wj;
        else if (it >= 9) nbr_idx[row * KNN + (it - 9)] = wj;
      }
      if (((wj >> 2) & 63) == lane) { dr[wj] = 0xFFFFFFFFu; rescan(); }
    }
  }
}

// ---------------- K3: fused edge-conditioned conv ----------------
// 256 threads = 16 q (f-lanes) x 16 pp (edge slots) x 2 edges/thread.
// Edge e = pp + 16*k  ->  node k, neighbor slot pp. LDS ~66 KB -> 2 blocks/CU.
// No min-waves bound: VGPRs free (~160), no spill.
__global__ __launch_bounds__(256) void k_edge(
    const float* __restrict__ h,
    const int* __restrict__ ctr_idx, const int* __restrict__ nbr_idx,
    const float* __restrict__ W_lab, const float* __restrict__ b_lab,
    const float* __restrict__ W1, const float* __restrict__ b1,
    const float* __restrict__ W2, const float* __restrict__ b2,
    const float* __restrict__ Wl, const float* __restrict__ bl,
    float* __restrict__ out)
{
  __shared__ __align__(16) float WT[264 * FI];      // 46.4 KB: r-half of W1/W2, transposed
  __shared__ __align__(16) float Wlab_s[FI * FI];   // 7.7 KB: W_lab transposed
  __shared__ __align__(16) float x1s[EPB][FI];
  __shared__ __align__(16) float lbs[EPB][FI];      // labels, then lab
  __shared__ __align__(16) float hcs[NPB][FI];
  __shared__ float tfs[EPB][RK];
  __shared__ float oacc[NPB][FI];

  const int tid = threadIdx.x;
  const int b = blockIdx.x;
  const int q = tid & 15;        // f-lane
  const int pp = tid >> 4;       // edge slot (0..15)

  // stage transposed column-block [n0, n0+nh) of W[44][ldw] into WT[nl*44+c]
  auto stageW = [&](const float* __restrict__ W, int ldw, int n0, int nh) {
    for (int task = tid; task < nh * 11; task += 256) {
      int nl = task % nh, cc = task / nh;
      int n = n0 + nl;
      float4 wv;
      wv.x = W[(size_t)(4 * cc + 0) * ldw + n];
      wv.y = W[(size_t)(4 * cc + 1) * ldw + n];
      wv.z = W[(size_t)(4 * cc + 2) * ldw + n];
      wv.w = W[(size_t)(4 * cc + 3) * ldw + n];
      *reinterpret_cast<float4*>(&WT[nl * FI + 4 * cc]) = wv;
    }
  };

  // ---- gather + stage W_lab + stage W1 first half ----
  for (int t = tid; t < NPB * FI; t += 256) oacc[t / FI][t % FI] = 0.f;
  for (int t = tid; t < NPB * FI; t += 256) {
    int nn = t / FI, c = t % FI;
    hcs[nn][c] = h[(size_t)ctr_idx[b * NPB + nn] * FI + c];
  }
  for (int t = tid; t < EPB * FI; t += 256) {
    int e = t / FI, c = t % FI;
    int nb = nbr_idx[(b * NPB + (e >> 4)) * KNN + (e & 15)];
    x1s[e][c] = h[(size_t)nb * FI + c];
  }
  for (int t = tid; t < FI * FI; t += 256) {
    int c = t / FI, f = t % FI;
    Wlab_s[f * FI + c] = W_lab[t];
  }
  stageW(W1, RK * FI, 0, 264);
  __syncthreads();
  for (int t = tid; t < EPB * FI; t += 256) {
    int e = t / FI, c = t % FI;
    lbs[e][c] = x1s[e][c] - hcs[e >> 4][c];
  }
  __syncthreads();

  // ---- P1: lab = leaky_relu(labels @ W_lab + b_lab); dl = ||labels||^2 ----
  float dl0 = 0.f, dl1 = 0.f;
#pragma unroll
  for (int cc = 0; cc < 11; cc++) {
    float4 a4 = *reinterpret_cast<const float4*>(&lbs[pp][4 * cc]);
    float4 b4 = *reinterpret_cast<const float4*>(&lbs[pp + 16][4 * cc]);
    dl0 += a4.x*a4.x + a4.y*a4.y + a4.z*a4.z + a4.w*a4.w;
    dl1 += b4.x*b4.x + b4.y*b4.y + b4.z*b4.z + b4.w*b4.w;
  }
  float la0[3], la1[3];
#pragma unroll
  for (int m = 0; m < 3; m++) {
    int f = q + 16 * m;
    if (f < FI) {
      float bb = b_lab[f];
      float th0 = bb, th1 = bb;
      const float4* Wn = reinterpret_cast<const float4*>(&Wlab_s[f * FI]);
#pragma unroll
      for (int cc = 0; cc < 11; cc++) {
        float4 w4 = Wn[cc];
        float4 a4 = *reinterpret_cast<const float4*>(&lbs[pp][4 * cc]);
        float4 b4 = *reinterpret_cast<const float4*>(&lbs[pp + 16][4 * cc]);
        th0 += w4.x*a4.x + w4.y*a4.y + w4.z*a4.z + w4.w*a4.w;
        th1 += w4.x*b4.x + w4.y*b4.y + w4.z*b4.z + w4.w*b4.w;
      }
      la0[m] = th0 >= 0.f ? th0 : 0.2f * th0;
      la1[m] = th1 >= 0.f ? th1 : 0.2f * th1;
    }
  }
  float xsl0[3], xsl1[3];
#pragma unroll
  for (int m = 0; m < 3; m++) {
    int f = q + 16 * m;
    if (f < FI) { xsl0[m] = x1s[pp][f]; xsl1[m] = x1s[pp + 16][f]; }
  }
  __syncthreads();                 // all labels reads done
#pragma unroll
  for (int m = 0; m < 3; m++) {
    int f = q + 16 * m;
    if (f < FI) { lbs[pp][f] = la0[m]; lbs[pp + 16][f] = la1[m]; }
  }
  __syncthreads();                 // lab ready

  // full lab rows into registers (88 VGPR)
  float4 lab0[11], lab1[11];
#pragma unroll
  for (int cc = 0; cc < 11; cc++) {
    lab0[cc] = *reinterpret_cast<const float4*>(&lbs[pp][4 * cc]);
    lab1[cc] = *reinterpret_cast<const float4*>(&lbs[pp + 16][4 * cc]);
  }

  // ---- P2: t[e][r] = sum_f (b1 + lab@W1)[r,f] * x1[e,f], two r-halves ----
  auto p2 = [&](int rbase, int rcount) {
    for (int rl = 0; rl < rcount; rl++) {
      int r = rbase + rl;
      float tp0 = 0.f, tp1 = 0.f;
#pragma unroll
      for (int m = 0; m < 3; m++) {
        int f = q + 16 * m;
        if (f < FI) {
          float bb = b1[r * FI + f];
          float th0 = bb, th1 = bb;
          const float4* Wn = reinterpret_cast<const float4*>(&WT[(rl * FI + f) * FI]);
#pragma unroll
          for (int cc = 0; cc < 11; cc++) {
            float4 w4 = Wn[cc];
            float4 a4 = lab0[cc], b4 = lab1[cc];
            th0 += w4.x*a4.x + w4.y*a4.y + w4.z*a4.z + w4.w*a4.w;
            th1 += w4.x*b4.x + w4.y*b4.y + w4.z*b4.z + w4.w*b4.w;
          }
          tp0 += th0 * xsl0[m];
          tp1 += th1 * xsl1[m];
        }
      }
#pragma unroll
      for (int off = 1; off < 16; off <<= 1) {
        tp0 += __shfl_xor(tp0, off, 64);
        tp1 += __shfl_xor(tp1, off, 64);
      }
      if (q == 0) { tfs[pp][r] = tp0; tfs[pp + 16][r] = tp1; }
    }
  };
  p2(0, 6);
  __syncthreads();
  stageW(W1, RK * FI, 264, 220);
  __syncthreads();
  p2(6, 5);
  __syncthreads();

  // ---- P3: t *= (lab @ W_thl + b_thl); stage W2 first half ----
  if (q < RK) {
    float tl0 = bl[q], tl1 = bl[q];
#pragma unroll
    for (int cc = 0; cc < 11; cc++) {
#pragma unroll
      for (int i = 0; i < 4; i++) {
        float wv = Wl[(size_t)(4 * cc + i) * RK + q];
        float a = i == 0 ? lab0[cc].x : i == 1 ? lab0[cc].y : i == 2 ? lab0[cc].z : lab0[cc].w;
        float bt = i == 0 ? lab1[cc].x : i == 1 ? lab1[cc].y : i == 2 ? lab1[cc].z : lab1[cc].w;
        tl0 += a * wv;
        tl1 += bt * wv;
      }
    }
    tfs[pp][q] *= tl0;
    tfs[pp + 16][q] *= tl1;
  }
  stageW(W2, RK * FI, 0, 264);
  __syncthreads();

  // ---- P4: x[e][f] = sum_r (b2 + lab@W2)[r,f] * t'[e][r], two r-halves ----
  float xo0[3] = {0, 0, 0}, xo1[3] = {0, 0, 0};
  auto p4 = [&](int rbase, int rcount) {
    for (int rl = 0; rl < rcount; rl++) {
      int r = rbase + rl;
      float t0 = tfs[pp][r], t1 = tfs[pp + 16][r];
#pragma unroll
      for (int m = 0; m < 3; m++) {
        int f = q + 16 * m;
        if (f < FI) {
          float bb = b2[r * FI + f];
          float th0 = bb, th1 = bb;
          const float4* Wn = reinterpret_cast<const float4*>(&WT[(rl * FI + f) * FI]);
#pragma unroll
          for (int cc = 0; cc < 11; cc++) {
            float4 w4 = Wn[cc];
            float4 a4 = lab0[cc], b4 = lab1[cc];
            th0 += w4.x*a4.x + w4.y*a4.y + w4.z*a4.z + w4.w*a4.w;
            th1 += w4.x*b4.x + w4.y*b4.y + w4.z*b4.z + w4.w*b4.w;
          }
          xo0[m] += th0 * t0;
          xo1[m] += th1 * t1;
        }
      }
    }
  };
  p4(0, 6);
  __syncthreads();
  stageW(W2, RK * FI, 264, 220);
  __syncthreads();
  p4(6, 5);

  // ---- epilogue: distance weight, reduce over pp, atomic into oacc ----
  float w0 = expf(-dl0 / 10.0f) * (1.0f / 16.0f);
  float w1 = expf(-dl1 / 10.0f) * (1.0f / 16.0f);
  const int lane = tid & 63;
#pragma unroll
  for (int m = 0; m < 3; m++) {
    int f = q + 16 * m;
    if (f < FI) {
      float v0 = xo0[m] * w0;
      float v1 = xo1[m] * w1;
      v0 += __shfl_xor(v0, 16, 64); v0 += __shfl_xor(v0, 32, 64);
      v1 += __shfl_xor(v1, 16, 64); v1 += __shfl_xor(v1, 32, 64);
      if (lane < 16) { atomicAdd(&oacc[0][f], v0); atomicAdd(&oacc[1][f], v1); }
    }
  }
  __syncthreads();
  for (int t = tid; t < NPB * FI; t += 256) {
    int nn = t / FI, c = t % FI;
    out[(size_t)(b * NPB + nn) * FI + c] = oacc[nn][c];
  }
}

extern "C" void kernel_launch(void* const* d_in, const int* in_sizes, int n_in,
                              void* d_out, int out_size, void* d_ws, size_t ws_size,
                              hipStream_t stream) {
  const float* h     = (const float*)d_in[0];
  const float* mask  = (const float*)d_in[1];
  const float* W_lab = (const float*)d_in[2];
  const float* b_lab = (const float*)d_in[3];
  const float* W1    = (const float*)d_in[4];
  const float* b1    = (const float*)d_in[5];
  const float* W2    = (const float*)d_in[6];
  const float* b2    = (const float*)d_in[7];
  const float* Wl    = (const float*)d_in[8];
  const float* bl    = (const float*)d_in[9];

  float* sq = (float*)d_ws;
  int* ctr  = (int*)(sq + N);
  int* nbr  = ctr + N;

  k_sqnorm<<<N / 256, 256, 0, stream>>>(h, sq);
  k_dist_topk<<<N / NROW, 256, 0, stream>>>(h, sq, mask, ctr, nbr);
  k_edge<<<N / NPB, 256, 0, stream>>>(h, ctr, nbr, W_lab, b_lab, W1, b1, W2, b2, Wl, bl, (float*)d_out);
}

// Round 4
// 293.611 us; speedup vs baseline: 8.7739x; 3.0039x over previous
//
#include <hip/hip_runtime.h>
#include <float.h>

#define N 4096
#define FI 44
#define RK 11
#define KNN 16
#define NSEL 25   // K + 9 ranks kept
#define NROW 4
#define ME 496    // padded reduction dim: 484 (c,r) + 11 bias + 1 pad

typedef unsigned long long u64;
typedef unsigned int u32;

// ---------------- K0: sq norms + h transpose ----------------
__global__ __launch_bounds__(256) void k_prep(const float* __restrict__ h,
                                              float* __restrict__ sq,
                                              float* __restrict__ hT) {
  int n = blockIdx.x * 256 + threadIdx.x;
  const float4* hr = reinterpret_cast<const float4*>(h + (size_t)n * FI);
  float v[FI];
  float s = 0.f;
#pragma unroll
  for (int c4 = 0; c4 < 11; c4++) {
    float4 x = hr[c4];
    v[4*c4] = x.x; v[4*c4+1] = x.y; v[4*c4+2] = x.z; v[4*c4+3] = x.w;
    s += x.x*x.x + x.y*x.y + x.z*x.z + x.w*x.w;
  }
  sq[n] = s;
#pragma unroll
  for (int c = 0; c < FI; c++) hT[c * N + n] = v[c];   // coalesced per c
}

// ---------------- K2: distance rows + top-25 via threshold + bitonic ----------------
__global__ __launch_bounds__(256) void k_dist_topk(const float* __restrict__ hT,
                                                   const float* __restrict__ sq,
                                                   const float* __restrict__ mask,
                                                   int* __restrict__ ctr_idx,
                                                   int* __restrict__ nbr_idx) {
  __shared__ __align__(16) u32 drow[NROW][N];     // 64 KB mapped keys
  __shared__ __align__(16) float hi[NROW][FI];
  __shared__ float sqi[NROW];
  __shared__ u64 cbuf[NROW][128];
  __shared__ int cnts[NROW];
  const int tid = threadIdx.x;
  const int r0 = blockIdx.x * NROW;

  if (tid < NROW) { cnts[tid] = 0; sqi[tid] = sq[r0 + tid]; }
  for (int t = tid; t < NROW * FI; t += 256) {
    int rr = t / FI, c = t % FI;
    hi[rr][c] = hT[c * N + (r0 + rr)];
  }
  __syncthreads();

  for (int s = 0; s < N / 256; s++) {
    int j = s * 256 + tid;
    float d0 = 0.f, d1 = 0.f, d2 = 0.f, d3 = 0.f;
#pragma unroll
    for (int c4 = 0; c4 < 11; c4++) {
      float v0 = hT[(4*c4+0) * N + j];
      float v1 = hT[(4*c4+1) * N + j];
      float v2 = hT[(4*c4+2) * N + j];
      float v3 = hT[(4*c4+3) * N + j];
      float4 h0 = *reinterpret_cast<const float4*>(&hi[0][4*c4]);
      float4 h1 = *reinterpret_cast<const float4*>(&hi[1][4*c4]);
      float4 h2 = *reinterpret_cast<const float4*>(&hi[2][4*c4]);
      float4 h3 = *reinterpret_cast<const float4*>(&hi[3][4*c4]);
      d0 += h0.x*v0 + h0.y*v1 + h0.z*v2 + h0.w*v3;
      d1 += h1.x*v0 + h1.y*v1 + h1.z*v2 + h1.w*v3;
      d2 += h2.x*v0 + h2.y*v1 + h2.z*v2 + h2.w*v3;
      d3 += h3.x*v0 + h3.y*v1 + h3.z*v2 + h3.w*v3;
    }
    float sqj = sq[j];
    float dd[4] = {d0, d1, d2, d3};
#pragma unroll
    for (int rr = 0; rr < NROW; rr++) {
      int row = r0 + rr;
      float D = fabsf(sqi[rr] + sqj - 2.f * dd[rr]) * mask[(size_t)row * N + j];
      if (j == row) D -= 2.f;
      u32 u = __float_as_uint(D);
      u ^= (u32)((int)u >> 31) | 0x80000000u;   // monotonic map
      drow[rr][j] = u;
    }
  }
  __syncthreads();

  const int w = tid >> 6, lane = tid & 63;
  u32* dr = drow[w];
  const u64 UMAX = ~0ull;
  const int row = r0 + w;

  u64 lm = UMAX;
#pragma unroll
  for (int t = 0; t < 16; t++) {
    uint4 v4 = *reinterpret_cast<const uint4*>(dr + 4 * (lane + 64 * t));
    u64 j0 = (u64)(4 * lane + 256 * t);
    u64 k0 = ((u64)v4.x << 12) | j0;
    u64 k1 = ((u64)v4.y << 12) | (j0 + 1);
    u64 k2 = ((u64)v4.z << 12) | (j0 + 2);
    u64 k3 = ((u64)v4.w << 12) | (j0 + 3);
    u64 m01 = k0 < k1 ? k0 : k1;
    u64 m23 = k2 < k3 ? k2 : k3;
    u64 m = m01 < m23 ? m01 : m23;
    lm = m < lm ? m : lm;
  }

  auto bitonic64 = [&](u64 v) -> u64 {
#pragma unroll
    for (int kk = 2; kk <= 64; kk <<= 1) {
#pragma unroll
      for (int jj = kk >> 1; jj > 0; jj >>= 1) {
        u64 o = __shfl_xor(v, jj, 64);
        bool lower = (lane & jj) == 0;
        bool asc = (lane & kk) == 0;
        u64 mn = o < v ? o : v;
        u64 mx = o < v ? v : o;
        v = (lower == asc) ? mn : mx;
      }
    }
    return v;
  };

  u64 sv = bitonic64(lm);
  u64 T = __shfl(sv, 24, 64);

#pragma unroll
  for (int t = 0; t < 16; t++) {
    uint4 v4 = *reinterpret_cast<const uint4*>(dr + 4 * (lane + 64 * t));
    u64 j0 = (u64)(4 * lane + 256 * t);
    u64 kz0 = ((u64)v4.x << 12) | j0;
    u64 kz1 = ((u64)v4.y << 12) | (j0 + 1);
    u64 kz2 = ((u64)v4.z << 12) | (j0 + 2);
    u64 kz3 = ((u64)v4.w << 12) | (j0 + 3);
    if (kz0 <= T) { int p = atomicAdd(&cnts[w], 1); if (p < 128) cbuf[w][p] = kz0; }
    if (kz1 <= T) { int p = atomicAdd(&cnts[w], 1); if (p < 128) cbuf[w][p] = kz1; }
    if (kz2 <= T) { int p = atomicAdd(&cnts[w], 1); if (p < 128) cbuf[w][p] = kz2; }
    if (kz3 <= T) { int p = atomicAdd(&cnts[w], 1); if (p < 128) cbuf[w][p] = kz3; }
  }
  __syncthreads();

  int cnt = cnts[w];
  if (cnt <= 64) {
    u64 cv = (lane < cnt) ? cbuf[w][lane] : UMAX;
    cv = bitonic64(cv);
    int idx = (int)(cv & 4095ull);
    if (lane == 0) ctr_idx[row] = idx;
    if (lane >= 9 && lane < NSEL) nbr_idx[row * KNN + (lane - 9)] = idx;
  } else {
    u64 bkey;
    auto rescan = [&]() {
      u64 best = UMAX;
#pragma unroll
      for (int t = 0; t < 16; t++) {
        uint4 v4 = *reinterpret_cast<const uint4*>(dr + 4 * (lane + 64 * t));
        u64 j0 = (u64)(4 * lane + 256 * t);
        u64 k0 = ((u64)v4.x << 12) | j0;
        u64 k1 = ((u64)v4.y << 12) | (j0 + 1);
        u64 k2 = ((u64)v4.z << 12) | (j0 + 2);
        u64 k3 = ((u64)v4.w << 12) | (j0 + 3);
        k0 = k0 < k1 ? k0 : k1;
        k2 = k2 < k3 ? k2 : k3;
        k0 = k0 < k2 ? k0 : k2;
        best = k0 < best ? k0 : best;
      }
      bkey = best;
    };
    rescan();
    for (int it = 0; it < NSEL; it++) {
      u64 kk = bkey;
#pragma unroll
      for (int off = 1; off < 64; off <<= 1) {
        u64 o = __shfl_xor(kk, off, 64);
        if (o < kk) kk = o;
      }
      int wj = (int)(kk & 4095ull);
      if (lane == 0) {
        if (it == 0) ctr_idx[row] = wj;
        else if (it >= 9) nbr_idx[row * KNN + (it - 9)] = wj;
      }
      if (((wj >> 2) & 63) == lane) { dr[wj] = 0xFFFFFFFFu; rescan(); }
    }
  }
}

// ---------------- K3: P1e[n][m] = dot44(h[n], Wr[m]) ----------------
// m = r*44+c (m<484): Wr[m] = W1[c, r*44 .. r*44+43]; m=484+r: b1[r]; m=495: 0.
__global__ __launch_bounds__(256) void k_P1(const float* __restrict__ h,
                                            const float* __restrict__ W1,
                                            const float* __restrict__ b1,
                                            float* __restrict__ P1e) {
  __shared__ __align__(16) float Wr[ME][FI];   // 87.3 KB
  const int tid = threadIdx.x;
  for (int t = tid; t < 484 * 11; t += 256) {
    int m = t / 11, k4 = t % 11;
    int r = m / FI, c = m % FI;
    float4 wv = *reinterpret_cast<const float4*>(W1 + (size_t)c * 484 + r * FI + 4 * k4);
    *reinterpret_cast<float4*>(&Wr[m][4 * k4]) = wv;
  }
  for (int t = tid; t < 11 * 11; t += 256) {
    int r = t / 11, k4 = t % 11;
    float4 wv = *reinterpret_cast<const float4*>(b1 + r * FI + 4 * k4);
    *reinterpret_cast<float4*>(&Wr[484 + r][4 * k4]) = wv;
  }
  for (int t = tid; t < 11; t += 256) { }
  if (tid < 11) *reinterpret_cast<float4*>(&Wr[495][4 * tid]) = make_float4(0.f, 0.f, 0.f, 0.f);
  __syncthreads();

  const int n = blockIdx.x * 64 + (tid >> 2);
  const int g = tid & 3;
  float4 hreg[11];
  const float4* hr = reinterpret_cast<const float4*>(h + (size_t)n * FI);
#pragma unroll
  for (int k4 = 0; k4 < 11; k4++) hreg[k4] = hr[k4];

  for (int mi = 0; mi < 124; mi++) {
    int m = g + 4 * mi;
    float acc = 0.f;
#pragma unroll
    for (int k4 = 0; k4 < 11; k4++) {
      float4 wv = *reinterpret_cast<const float4*>(&Wr[m][4 * k4]);
      acc += wv.x*hreg[k4].x + wv.y*hreg[k4].y + wv.z*hreg[k4].z + wv.w*hreg[k4].w;
    }
    P1e[(size_t)n * ME + m] = acc;
  }
}

// ---------------- K4: lab + wexp ----------------
// block: 64 edges (4 nodes). lab[e][f] = leakyrelu(labels@W_lab + b_lab).
__global__ __launch_bounds__(256) void k_lab(const float* __restrict__ h,
                                             const int* __restrict__ ctr_idx,
                                             const int* __restrict__ nbr_idx,
                                             const float* __restrict__ W_lab,
                                             const float* __restrict__ b_lab,
                                             float* __restrict__ lab,
                                             float* __restrict__ wexp) {
  __shared__ __align__(16) float WlabT[FI][FI];   // [f][c]
  __shared__ __align__(16) float lbl[64][FI];
  __shared__ int nbrL[64];
  __shared__ int ctrL[4];
  const int tid = threadIdx.x;
  const int b = blockIdx.x;

  if (tid < 64) nbrL[tid] = nbr_idx[b * 64 + tid];
  if (tid < 4) ctrL[tid] = ctr_idx[b * 4 + tid];
  for (int t = tid; t < FI * FI; t += 256) {
    int c = t / FI, f = t % FI;
    WlabT[f][c] = W_lab[t];
  }
  __syncthreads();
  for (int t = tid; t < 64 * FI; t += 256) {
    int e = t / FI, c = t % FI;
    lbl[e][c] = h[(size_t)nbrL[e] * FI + c] - h[(size_t)ctrL[e >> 4] * FI + c];
  }
  __syncthreads();

  if (tid < 64) {
    float s = 0.f;
#pragma unroll
    for (int c4 = 0; c4 < 11; c4++) {
      float4 v = *reinterpret_cast<const float4*>(&lbl[tid][4 * c4]);
      s += v.x*v.x + v.y*v.y + v.z*v.z + v.w*v.w;
    }
    wexp[b * 64 + tid] = expf(-s * 0.1f) * (1.0f / 16.0f);
  }

  const int e = tid >> 2;      // edge 0..63
  const int g = tid & 3;
#pragma unroll
  for (int u = 0; u < 11; u++) {
    int f = g + 4 * u;
    float acc = b_lab[f];
#pragma unroll
    for (int c4 = 0; c4 < 11; c4++) {
      float4 wv = *reinterpret_cast<const float4*>(&WlabT[f][4 * c4]);
      float4 lv = *reinterpret_cast<const float4*>(&lbl[e][4 * c4]);
      acc += wv.x*lv.x + wv.y*lv.y + wv.z*lv.z + wv.w*lv.w;
    }
    lab[(size_t)(b * 64 + e) * FI + f] = acc >= 0.f ? acc : 0.2f * acc;
  }
}

// ---------------- K5: tprime[e][r] = wexp*(dot(lab,P1[nbr]) + B1X)*(lab@Wl + bl) ----------------
// 16 lanes per edge over c; 16 edges per block.
__global__ __launch_bounds__(256) void k_t(const float* __restrict__ lab,
                                           const int* __restrict__ nbr_idx,
                                           const float* __restrict__ P1e,
                                           const float* __restrict__ Wl,
                                           const float* __restrict__ bl,
                                           const float* __restrict__ wexp,
                                           float* __restrict__ tpr) {
  __shared__ float WlT[RK][FI];
  const int tid = threadIdx.x;
  for (int t = tid; t < FI * RK; t += 256) {
    int c = t / RK, r = t % RK;
    WlT[r][c] = Wl[t];
  }
  __syncthreads();

  const int eL = tid >> 4;           // 0..15
  const int l16 = tid & 15;
  const int e = blockIdx.x * 16 + eL;
  const int n1 = nbr_idx[e];
  float labv[3];
#pragma unroll
  for (int m = 0; m < 3; m++) {
    int c = l16 + 16 * m;
    labv[m] = (c < FI) ? lab[(size_t)e * FI + c] : 0.f;
  }
  const float* P1r = P1e + (size_t)n1 * ME;
  float myt = 0.f, mytl = 0.f;
  for (int r = 0; r < RK; r++) {
    float tp = 0.f, tlp = 0.f;
#pragma unroll
    for (int m = 0; m < 3; m++) {
      int c = l16 + 16 * m;
      if (c < FI) {
        tp += labv[m] * P1r[r * FI + c];
        tlp += labv[m] * WlT[r][c];
      }
    }
#pragma unroll
    for (int off = 1; off < 16; off <<= 1) {
      tp += __shfl_xor(tp, off, 64);
      tlp += __shfl_xor(tlp, off, 64);
    }
    if (l16 == r) { myt = tp; mytl = tlp; }
  }
  if (l16 < RK) {
    float tfull = myt + P1r[484 + l16];
    float tl = mytl + bl[l16];
    tpr[(size_t)e * 12 + l16] = tfull * tl * wexp[e];
  }
}

// ---------------- K6: Ge[n][r*44+c] = sum_k lab[e,c]*tpr[e,r]; Ge[n][484+r] = sum_k tpr ----------------
__global__ __launch_bounds__(64) void k_G(const float* __restrict__ lab,
                                          const float* __restrict__ tpr,
                                          float* __restrict__ Ge) {
  __shared__ float tpL[KNN][RK];
  const int tid = threadIdx.x;
  const int n = blockIdx.x;
  for (int t = tid; t < KNN * RK; t += 64) {
    int k = t / RK, r = t % RK;
    tpL[k][r] = tpr[(size_t)(n * KNN + k) * 12 + r];
  }
  __syncthreads();

  const int c = tid;
  if (c < FI) {
    float acc[RK];
#pragma unroll
    for (int r = 0; r < RK; r++) acc[r] = 0.f;
    for (int k = 0; k < KNN; k++) {
      float lv = lab[(size_t)(n * KNN + k) * FI + c];
#pragma unroll
      for (int r = 0; r < RK; r++) acc[r] += lv * tpL[k][r];
    }
#pragma unroll
    for (int r = 0; r < RK; r++) Ge[(size_t)n * ME + r * FI + c] = acc[r];
  } else if (c < 55) {
    int r = c - FI;
    float ss = 0.f;
    for (int k = 0; k < KNN; k++) ss += tpL[k][r];
    Ge[(size_t)n * ME + 484 + r] = ss;
  } else if (c == 55) {
    Ge[(size_t)n * ME + 495] = 0.f;
  }
}

// ---------------- K7: out[n][fo] = sum_m Ge[n][m] * W2eT[fo][m] ----------------
__global__ __launch_bounds__(256) void k_out(const float* __restrict__ Ge,
                                             const float* __restrict__ W2,
                                             const float* __restrict__ b2,
                                             float* __restrict__ out) {
  __shared__ __align__(16) float W2eT[FI][ME];   // 87.3 KB
  const int tid = threadIdx.x;
  for (int t = tid; t < 484 * 11; t += 256) {
    int m = t / 11, k4 = t % 11;
    int r = m / FI, c = m % FI;
    float4 wv = *reinterpret_cast<const float4*>(W2 + (size_t)c * 484 + r * FI + 4 * k4);
    W2eT[4*k4+0][m] = wv.x; W2eT[4*k4+1][m] = wv.y; W2eT[4*k4+2][m] = wv.z; W2eT[4*k4+3][m] = wv.w;
  }
  for (int t = tid; t < 11 * 11; t += 256) {
    int r = t / 11, k4 = t % 11;
    float4 wv = *reinterpret_cast<const float4*>(b2 + r * FI + 4 * k4);
    W2eT[4*k4+0][484+r] = wv.x; W2eT[4*k4+1][484+r] = wv.y; W2eT[4*k4+2][484+r] = wv.z; W2eT[4*k4+3][484+r] = wv.w;
  }
  if (tid < FI) W2eT[tid][495] = 0.f;
  __syncthreads();

  const int n = blockIdx.x * 64 + (tid >> 2);
  const int g = tid & 3;
  const float4* gr = reinterpret_cast<const float4*>(Ge + (size_t)n * ME);
  float acc[11];
#pragma unroll
  for (int u = 0; u < 11; u++) acc[u] = 0.f;
  for (int mc = 0; mc < ME / 4; mc++) {
    float4 g4 = gr[mc];
#pragma unroll
    for (int u = 0; u < 11; u++) {
      int fo = g + 4 * u;
      float4 w4 = *reinterpret_cast<const float4*>(&W2eT[fo][4 * mc]);
      acc[u] += g4.x*w4.x + g4.y*w4.y + g4.z*w4.z + g4.w*w4.w;
    }
  }
#pragma unroll
  for (int u = 0; u < 11; u++) out[(size_t)n * FI + g + 4 * u] = acc[u];
}

extern "C" void kernel_launch(void* const* d_in, const int* in_sizes, int n_in,
                              void* d_out, int out_size, void* d_ws, size_t ws_size,
                              hipStream_t stream) {
  const float* h     = (const float*)d_in[0];
  const float* mask  = (const float*)d_in[1];
  const float* W_lab = (const float*)d_in[2];
  const float* b_lab = (const float*)d_in[3];
  const float* W1    = (const float*)d_in[4];
  const float* b1    = (const float*)d_in[5];
  const float* W2    = (const float*)d_in[6];
  const float* b2    = (const float*)d_in[7];
  const float* Wl    = (const float*)d_in[8];
  const float* bl    = (const float*)d_in[9];

  float* sqw  = (float*)d_ws;                       // [4096]
  float* hT   = sqw + N;                            // [44*4096]
  int*   ctr  = (int*)(hT + (size_t)FI * N);        // [4096]
  int*   nbr  = ctr + N;                            // [65536]
  float* P1e  = (float*)(nbr + N * KNN);            // [4096*496]
  float* lab  = P1e + (size_t)N * ME;               // [65536*44]
  float* wexp = lab + (size_t)N * KNN * FI;         // [65536]
  float* tpr  = wexp + (size_t)N * KNN;             // [65536*12]
  float* Ge   = tpr + (size_t)N * KNN * 12;         // [4096*496]

  k_prep<<<N / 256, 256, 0, stream>>>(h, sqw, hT);
  k_dist_topk<<<N / NROW, 256, 0, stream>>>(hT, sqw, mask, ctr, nbr);
  k_P1<<<N / 64, 256, 0, stream>>>(h, W1, b1, P1e);
  k_lab<<<N * KNN / 64, 256, 0, stream>>>(h, ctr, nbr, W_lab, b_lab, lab, wexp);
  k_t<<<N * KNN / 16, 256, 0, stream>>>(lab, nbr, P1e, Wl, bl, wexp, tpr);
  k_G<<<N, 64, 0, stream>>>(lab, tpr, Ge);
  k_out<<<N / 64, 256, 0, stream>>>(Ge, W2, b2, (float*)d_out);
}

// Round 5
// 220.550 us; speedup vs baseline: 11.6805x; 1.3313x over previous
//
#include <hip/hip_runtime.h>
#include <float.h>

#define N 4096
#define FI 44
#define RK 11
#define KNN 16
#define NSEL 25   // K + 9 ranks kept
#define NROW 4
#define ME 496    // padded reduction dim: 484 (c,r) + 11 bias + 1 pad

typedef unsigned long long u64;
typedef unsigned int u32;

// ---------------- K0: sq norms + h transpose ----------------
__global__ __launch_bounds__(256) void k_prep(const float* __restrict__ h,
                                              float* __restrict__ sq,
                                              float* __restrict__ hT) {
  int n = blockIdx.x * 256 + threadIdx.x;
  const float4* hr = reinterpret_cast<const float4*>(h + (size_t)n * FI);
  float v[FI];
  float s = 0.f;
#pragma unroll
  for (int c4 = 0; c4 < 11; c4++) {
    float4 x = hr[c4];
    v[4*c4] = x.x; v[4*c4+1] = x.y; v[4*c4+2] = x.z; v[4*c4+3] = x.w;
    s += x.x*x.x + x.y*x.y + x.z*x.z + x.w*x.w;
  }
  sq[n] = s;
#pragma unroll
  for (int c = 0; c < FI; c++) hT[c * N + n] = v[c];   // coalesced per c
}

// ---------------- K2: distance rows + top-25, keys in registers ----------------
// Per thread: 4 rows x 16 cols of keys in VGPRs. Threshold T[r] = 25th
// smallest of 64 group-minima (groups of 4 threads) => >=25 keys <= T.
// Compact (value<<12|col) u64 candidates to LDS, one 128-wide bitonic sort
// per row gives exact jax.lax.top_k order (value, then smaller index).
__global__ __launch_bounds__(256) void k_dist_topk(const float* __restrict__ hT,
                                                   const float* __restrict__ sq,
                                                   const float* __restrict__ mask,
                                                   int* __restrict__ ctr_idx,
                                                   int* __restrict__ nbr_idx) {
  __shared__ __align__(16) float hi[NROW][FI];
  __shared__ float sqi[NROW];
  __shared__ u32 lmin[NROW][256];
  __shared__ u32 Tsh[NROW];
  __shared__ int cnts[NROW];
  __shared__ u64 cbuf[NROW][128];
  const int tid = threadIdx.x;
  const int r0 = blockIdx.x * NROW;

  if (tid < NROW) { cnts[tid] = 0; sqi[tid] = sq[r0 + tid]; }
  for (int t = tid; t < NROW * FI; t += 256) {
    int rr = t / FI, c = t % FI;
    hi[rr][c] = hT[c * N + (r0 + rr)];
  }
  __syncthreads();

  // ---- sweep: acc[rr][s] = dot(h[r0+rr], h[j]), j = s*256+tid ----
  float acc[NROW][16];
#pragma unroll
  for (int rr = 0; rr < NROW; rr++)
#pragma unroll
    for (int s = 0; s < 16; s++) acc[rr][s] = 0.f;

  for (int c4 = 0; c4 < 11; c4++) {
    float4 h4[NROW];
#pragma unroll
    for (int rr = 0; rr < NROW; rr++) h4[rr] = *reinterpret_cast<const float4*>(&hi[rr][4 * c4]);
    const float* p0 = hT + (size_t)(4 * c4 + 0) * N + tid;
    const float* p1 = hT + (size_t)(4 * c4 + 1) * N + tid;
    const float* p2 = hT + (size_t)(4 * c4 + 2) * N + tid;
    const float* p3 = hT + (size_t)(4 * c4 + 3) * N + tid;
#pragma unroll
    for (int s = 0; s < 16; s++) {
      float v0 = p0[s * 256], v1 = p1[s * 256], v2 = p2[s * 256], v3 = p3[s * 256];
#pragma unroll
      for (int rr = 0; rr < NROW; rr++)
        acc[rr][s] += h4[rr].x * v0 + h4[rr].y * v1 + h4[rr].z * v2 + h4[rr].w * v3;
    }
  }

  // ---- finalize to monotonic-mapped u32 keys (exact reference formula) ----
  u32 key[NROW][16];
#pragma unroll
  for (int s = 0; s < 16; s++) {
    int j = s * 256 + tid;
    float sqj = sq[j];
#pragma unroll
    for (int rr = 0; rr < NROW; rr++) {
      float D = fabsf(sqi[rr] + sqj - 2.f * acc[rr][s]) * mask[(size_t)(r0 + rr) * N + j];
      if (j == r0 + rr) D -= 2.f;
      u32 u = __float_as_uint(D);
      u ^= (u32)((int)u >> 31) | 0x80000000u;
      key[rr][s] = u;
    }
  }

  // ---- per-thread minima ----
#pragma unroll
  for (int rr = 0; rr < NROW; rr++) {
    u32 m = key[rr][0];
#pragma unroll
    for (int s = 1; s < 16; s++) m = key[rr][s] < m ? key[rr][s] : m;
    lmin[rr][tid] = m;
  }
  __syncthreads();

  const int w = tid >> 6, lane = tid & 63;
  {
    u32 a = lmin[w][lane], b = lmin[w][64 + lane];
    u32 c = lmin[w][128 + lane], d = lmin[w][192 + lane];
    u32 g = a < b ? a : b;
    u32 g2 = c < d ? c : d;
    g = g2 < g ? g2 : g;
    // bitonic64 ascending over u32
#pragma unroll
    for (int kk = 2; kk <= 64; kk <<= 1)
#pragma unroll
      for (int jj = kk >> 1; jj > 0; jj >>= 1) {
        u32 o = __shfl_xor(g, jj, 64);
        bool low = (lane & jj) == 0, asc = (lane & kk) == 0;
        u32 mn = o < g ? o : g, mx = o < g ? g : o;
        g = (low == asc) ? mn : mx;
      }
    if (lane == 24) Tsh[w] = g;   // 25th smallest group-min
  }
  __syncthreads();

  // ---- compaction: keys <= T[r] -> cbuf ----
#pragma unroll
  for (int rr = 0; rr < NROW; rr++) {
    u32 Tr = Tsh[rr];
#pragma unroll
    for (int s = 0; s < 16; s++) {
      if (key[rr][s] <= Tr) {
        int p = atomicAdd(&cnts[rr], 1);
        if (p < 128) cbuf[rr][p] = ((u64)key[rr][s] << 12) | (u64)(s * 256 + tid);
      }
    }
  }
  __syncthreads();

  // ---- wave w: 128-wide bitonic sort of row w's candidates ----
  const u64 UMAX = ~0ull;
  int cnt = cnts[w];               // E~32; >128 unreachable for real data
  u64 v0 = (lane < cnt) ? cbuf[w][lane] : UMAX;
  u64 v1 = (64 + lane < cnt) ? cbuf[w][64 + lane] : UMAX;
#pragma unroll
  for (int kk = 2; kk <= 128; kk <<= 1) {
#pragma unroll
    for (int jj = kk >> 1; jj > 0; jj >>= 1) {
      if (jj >= 64) {
        bool asc = (lane & kk) == 0;
        u64 mn = v0 < v1 ? v0 : v1, mx = v0 < v1 ? v1 : v0;
        v0 = asc ? mn : mx; v1 = asc ? mx : mn;
      } else {
        bool low = (lane & jj) == 0;
        bool asc0 = (lane & kk) == 0;
        bool asc1 = ((64 + lane) & kk) == 0;
        u64 o0 = __shfl_xor(v0, jj, 64);
        v0 = (low == asc0) ? (o0 < v0 ? o0 : v0) : (o0 < v0 ? v0 : o0);
        u64 o1 = __shfl_xor(v1, jj, 64);
        v1 = (low == asc1) ? (o1 < v1 ? o1 : v1) : (o1 < v1 ? v1 : o1);
      }
    }
  }
  int row = r0 + w;
  int idx = (int)(v0 & 4095ull);
  if (lane == 0) ctr_idx[row] = idx;
  if (lane >= 9 && lane < NSEL) nbr_idx[row * KNN + (lane - 9)] = idx;
}

// ---------------- K3: P1e[n][m] = dot44(h[n], Wr[m]) ----------------
// m = r*44+c (m<484): Wr[m] = W1[c, r*44 .. r*44+43]; m=484+r: b1[r]; m=495: 0.
__global__ __launch_bounds__(256) void k_P1(const float* __restrict__ h,
                                            const float* __restrict__ W1,
                                            const float* __restrict__ b1,
                                            float* __restrict__ P1e) {
  __shared__ __align__(16) float Wr[ME][FI];   // 87.3 KB
  const int tid = threadIdx.x;
  for (int t = tid; t < 484 * 11; t += 256) {
    int m = t / 11, k4 = t % 11;
    int r = m / FI, c = m % FI;
    float4 wv = *reinterpret_cast<const float4*>(W1 + (size_t)c * 484 + r * FI + 4 * k4);
    *reinterpret_cast<float4*>(&Wr[m][4 * k4]) = wv;
  }
  for (int t = tid; t < 11 * 11; t += 256) {
    int r = t / 11, k4 = t % 11;
    float4 wv = *reinterpret_cast<const float4*>(b1 + r * FI + 4 * k4);
    *reinterpret_cast<float4*>(&Wr[484 + r][4 * k4]) = wv;
  }
  if (tid < 11) *reinterpret_cast<float4*>(&Wr[495][4 * tid]) = make_float4(0.f, 0.f, 0.f, 0.f);
  __syncthreads();

  const int n = blockIdx.x * 64 + (tid >> 2);
  const int g = tid & 3;
  float4 hreg[11];
  const float4* hr = reinterpret_cast<const float4*>(h + (size_t)n * FI);
#pragma unroll
  for (int k4 = 0; k4 < 11; k4++) hreg[k4] = hr[k4];

  for (int mi = 0; mi < 124; mi++) {
    int m = g + 4 * mi;
    float acc = 0.f;
#pragma unroll
    for (int k4 = 0; k4 < 11; k4++) {
      float4 wv = *reinterpret_cast<const float4*>(&Wr[m][4 * k4]);
      acc += wv.x*hreg[k4].x + wv.y*hreg[k4].y + wv.z*hreg[k4].z + wv.w*hreg[k4].w;
    }
    P1e[(size_t)n * ME + m] = acc;
  }
}

// ---------------- K4: lab + wexp ----------------
__global__ __launch_bounds__(256) void k_lab(const float* __restrict__ h,
                                             const int* __restrict__ ctr_idx,
                                             const int* __restrict__ nbr_idx,
                                             const float* __restrict__ W_lab,
                                             const float* __restrict__ b_lab,
                                             float* __restrict__ lab,
                                             float* __restrict__ wexp) {
  __shared__ __align__(16) float WlabT[FI][FI];   // [f][c]
  __shared__ __align__(16) float lbl[64][FI];
  __shared__ int nbrL[64];
  __shared__ int ctrL[4];
  const int tid = threadIdx.x;
  const int b = blockIdx.x;

  if (tid < 64) nbrL[tid] = nbr_idx[b * 64 + tid];
  if (tid < 4) ctrL[tid] = ctr_idx[b * 4 + tid];
  for (int t = tid; t < FI * FI; t += 256) {
    int c = t / FI, f = t % FI;
    WlabT[f][c] = W_lab[t];
  }
  __syncthreads();
  for (int t = tid; t < 64 * FI; t += 256) {
    int e = t / FI, c = t % FI;
    lbl[e][c] = h[(size_t)nbrL[e] * FI + c] - h[(size_t)ctrL[e >> 4] * FI + c];
  }
  __syncthreads();

  if (tid < 64) {
    float s = 0.f;
#pragma unroll
    for (int c4 = 0; c4 < 11; c4++) {
      float4 v = *reinterpret_cast<const float4*>(&lbl[tid][4 * c4]);
      s += v.x*v.x + v.y*v.y + v.z*v.z + v.w*v.w;
    }
    wexp[b * 64 + tid] = expf(-s * 0.1f) * (1.0f / 16.0f);
  }

  const int e = tid >> 2;      // edge 0..63
  const int g = tid & 3;
#pragma unroll
  for (int u = 0; u < 11; u++) {
    int f = g + 4 * u;
    float acc = b_lab[f];
#pragma unroll
    for (int c4 = 0; c4 < 11; c4++) {
      float4 wv = *reinterpret_cast<const float4*>(&WlabT[f][4 * c4]);
      float4 lv = *reinterpret_cast<const float4*>(&lbl[e][4 * c4]);
      acc += wv.x*lv.x + wv.y*lv.y + wv.z*lv.z + wv.w*lv.w;
    }
    lab[(size_t)(b * 64 + e) * FI + f] = acc >= 0.f ? acc : 0.2f * acc;
  }
}

// ---------------- K5: tprime[e][r] = wexp*(dot(lab,P1[nbr]) + B1X)*(lab@Wl + bl) ----------------
__global__ __launch_bounds__(256) void k_t(const float* __restrict__ lab,
                                           const int* __restrict__ nbr_idx,
                                           const float* __restrict__ P1e,
                                           const float* __restrict__ Wl,
                                           const float* __restrict__ bl,
                                           const float* __restrict__ wexp,
                                           float* __restrict__ tpr) {
  __shared__ float WlT[RK][FI];
  const int tid = threadIdx.x;
  for (int t = tid; t < FI * RK; t += 256) {
    int c = t / RK, r = t % RK;
    WlT[r][c] = Wl[t];
  }
  __syncthreads();

  const int eL = tid >> 4;           // 0..15
  const int l16 = tid & 15;
  const int e = blockIdx.x * 16 + eL;
  const int n1 = nbr_idx[e];
  float labv[3];
#pragma unroll
  for (int m = 0; m < 3; m++) {
    int c = l16 + 16 * m;
    labv[m] = (c < FI) ? lab[(size_t)e * FI + c] : 0.f;
  }
  const float* P1r = P1e + (size_t)n1 * ME;
  float myt = 0.f, mytl = 0.f;
  for (int r = 0; r < RK; r++) {
    float tp = 0.f, tlp = 0.f;
#pragma unroll
    for (int m = 0; m < 3; m++) {
      int c = l16 + 16 * m;
      if (c < FI) {
        tp += labv[m] * P1r[r * FI + c];
        tlp += labv[m] * WlT[r][c];
      }
    }
#pragma unroll
    for (int off = 1; off < 16; off <<= 1) {
      tp += __shfl_xor(tp, off, 64);
      tlp += __shfl_xor(tlp, off, 64);
    }
    if (l16 == r) { myt = tp; mytl = tlp; }
  }
  if (l16 < RK) {
    float tfull = myt + P1r[484 + l16];
    float tl = mytl + bl[l16];
    tpr[(size_t)e * 12 + l16] = tfull * tl * wexp[e];
  }
}

// ---------------- K6: Ge[n][r*44+c] = sum_k lab[e,c]*tpr[e,r]; Ge[n][484+r] = sum_k tpr ----------------
__global__ __launch_bounds__(64) void k_G(const float* __restrict__ lab,
                                          const float* __restrict__ tpr,
                                          float* __restrict__ Ge) {
  __shared__ float tpL[KNN][RK];
  const int tid = threadIdx.x;
  const int n = blockIdx.x;
  for (int t = tid; t < KNN * RK; t += 64) {
    int k = t / RK, r = t % RK;
    tpL[k][r] = tpr[(size_t)(n * KNN + k) * 12 + r];
  }
  __syncthreads();

  const int c = tid;
  if (c < FI) {
    float acc[RK];
#pragma unroll
    for (int r = 0; r < RK; r++) acc[r] = 0.f;
    for (int k = 0; k < KNN; k++) {
      float lv = lab[(size_t)(n * KNN + k) * FI + c];
#pragma unroll
      for (int r = 0; r < RK; r++) acc[r] += lv * tpL[k][r];
    }
#pragma unroll
    for (int r = 0; r < RK; r++) Ge[(size_t)n * ME + r * FI + c] = acc[r];
  } else if (c < 55) {
    int r = c - FI;
    float ss = 0.f;
    for (int k = 0; k < KNN; k++) ss += tpL[k][r];
    Ge[(size_t)n * ME + 484 + r] = ss;
  } else if (c == 55) {
    Ge[(size_t)n * ME + 495] = 0.f;
  }
}

// ---------------- K7: out[n][fo] = sum_m Ge[n][m] * W2eT[fo][m] ----------------
__global__ __launch_bounds__(256) void k_out(const float* __restrict__ Ge,
                                             const float* __restrict__ W2,
                                             const float* __restrict__ b2,
                                             float* __restrict__ out) {
  __shared__ __align__(16) float W2eT[FI][ME];   // 87.3 KB
  const int tid = threadIdx.x;
  for (int t = tid; t < 484 * 11; t += 256) {
    int m = t / 11, k4 = t % 11;
    int r = m / FI, c = m % FI;
    float4 wv = *reinterpret_cast<const float4*>(W2 + (size_t)c * 484 + r * FI + 4 * k4);
    W2eT[4*k4+0][m] = wv.x; W2eT[4*k4+1][m] = wv.y; W2eT[4*k4+2][m] = wv.z; W2eT[4*k4+3][m] = wv.w;
  }
  for (int t = tid; t < 11 * 11; t += 256) {
    int r = t / 11, k4 = t % 11;
    float4 wv = *reinterpret_cast<const float4*>(b2 + r * FI + 4 * k4);
    W2eT[4*k4+0][484+r] = wv.x; W2eT[4*k4+1][484+r] = wv.y; W2eT[4*k4+2][484+r] = wv.z; W2eT[4*k4+3][484+r] = wv.w;
  }
  if (tid < FI) W2eT[tid][495] = 0.f;
  __syncthreads();

  const int n = blockIdx.x * 64 + (tid >> 2);
  const int g = tid & 3;
  const float4* gr = reinterpret_cast<const float4*>(Ge + (size_t)n * ME);
  float acc[11];
#pragma unroll
  for (int u = 0; u < 11; u++) acc[u] = 0.f;
  for (int mc = 0; mc < ME / 4; mc++) {
    float4 g4 = gr[mc];
#pragma unroll
    for (int u = 0; u < 11; u++) {
      int fo = g + 4 * u;
      float4 w4 = *reinterpret_cast<const float4*>(&W2eT[fo][4 * mc]);
      acc[u] += g4.x*w4.x + g4.y*w4.y + g4.z*w4.z + g4.w*w4.w;
    }
  }
#pragma unroll
  for (int u = 0; u < 11; u++) out[(size_t)n * FI + g + 4 * u] = acc[u];
}

extern "C" void kernel_launch(void* const* d_in, const int* in_sizes, int n_in,
                              void* d_out, int out_size, void* d_ws, size_t ws_size,
                              hipStream_t stream) {
  const float* h     = (const float*)d_in[0];
  const float* mask  = (const float*)d_in[1];
  const float* W_lab = (const float*)d_in[2];
  const float* b_lab = (const float*)d_in[3];
  const float* W1    = (const float*)d_in[4];
  const float* b1    = (const float*)d_in[5];
  const float* W2    = (const float*)d_in[6];
  const float* b2    = (const float*)d_in[7];
  const float* Wl    = (const float*)d_in[8];
  const float* bl    = (const float*)d_in[9];

  float* sqw  = (float*)d_ws;                       // [4096]
  float* hT   = sqw + N;                            // [44*4096]
  int*   ctr  = (int*)(hT + (size_t)FI * N);        // [4096]
  int*   nbr  = ctr + N;                            // [65536]
  float* P1e  = (float*)(nbr + N * KNN);            // [4096*496]
  float* lab  = P1e + (size_t)N * ME;               // [65536*44]
  float* wexp = lab + (size_t)N * KNN * FI;         // [65536]
  float* tpr  = wexp + (size_t)N * KNN;             // [65536*12]
  float* Ge   = tpr + (size_t)N * KNN * 12;         // [4096*496]

  k_prep<<<N / 256, 256, 0, stream>>>(h, sqw, hT);
  k_dist_topk<<<N / NROW, 256, 0, stream>>>(hT, sqw, mask, ctr, nbr);
  k_P1<<<N / 64, 256, 0, stream>>>(h, W1, b1, P1e);
  k_lab<<<N * KNN / 64, 256, 0, stream>>>(h, ctr, nbr, W_lab, b_lab, lab, wexp);
  k_t<<<N * KNN / 16, 256, 0, stream>>>(lab, nbr, P1e, Wl, bl, wexp, tpr);
  k_G<<<N, 64, 0, stream>>>(lab, tpr, Ge);
  k_out<<<N / 64, 256, 0, stream>>>(Ge, W2, b2, (float*)d_out);
}

// Round 6
// 175.400 us; speedup vs baseline: 14.6871x; 1.2574x over previous
//
#include <hip/hip_runtime.h>
#include <float.h>

#define N 4096
#define FI 44
#define RK 11
#define KNN 16
#define NSEL 25   // K + 9 ranks kept
#define NROW 4
#define ME 496    // padded reduction dim: 484 (c,r) + 11 bias + 1 pad

typedef unsigned long long u64;
typedef unsigned int u32;

// ---------------- K0: sq norms + h transpose ----------------
__global__ __launch_bounds__(256) void k_prep(const float* __restrict__ h,
                                              float* __restrict__ sq,
                                              float* __restrict__ hT) {
  int n = blockIdx.x * 256 + threadIdx.x;
  const float4* hr = reinterpret_cast<const float4*>(h + (size_t)n * FI);
  float v[FI];
  float s = 0.f;
#pragma unroll
  for (int c4 = 0; c4 < 11; c4++) {
    float4 x = hr[c4];
    v[4*c4] = x.x; v[4*c4+1] = x.y; v[4*c4+2] = x.z; v[4*c4+3] = x.w;
    s += x.x*x.x + x.y*x.y + x.z*x.z + x.w*x.w;
  }
  sq[n] = s;
#pragma unroll
  for (int c = 0; c < FI; c++) hT[c * N + n] = v[c];   // coalesced per c
}

// ---------------- K2: distance rows + top-25, float4 sweep ----------------
// 512 threads; thread owns j in {4*tid+i} and {2048+4*tid+i} (i<4) for 4 rows.
// All hT/mask/sq reads are float4. Threshold T[r] = 25th smallest of 64
// group-minima (groups of 64 elements) => >=25 keys <= T. Compact u64
// (value<<12|col) candidates, one 128-wide bitonic sort per row gives exact
// jax.lax.top_k order (value asc, then smaller index).
__global__ __launch_bounds__(512) void k_dist_topk(const float* __restrict__ hT,
                                                   const float* __restrict__ sq,
                                                   const float* __restrict__ mask,
                                                   int* __restrict__ ctr_idx,
                                                   int* __restrict__ nbr_idx) {
  __shared__ __align__(16) float hi[NROW][FI];
  __shared__ float sqi4[NROW];
  __shared__ u32 lmin[NROW][512];     // 8 KB
  __shared__ u32 Tsh[NROW];
  __shared__ int cnts[NROW];
  __shared__ u64 cbuf[NROW][128];     // 4 KB
  const int tid = threadIdx.x;
  const int r0 = blockIdx.x * NROW;

  if (tid < NROW) { cnts[tid] = 0; sqi4[tid] = sq[r0 + tid]; }
  for (int t = tid; t < NROW * FI; t += 512) {
    int rr = t / FI, c = t % FI;
    hi[rr][c] = hT[c * N + (r0 + rr)];
  }
  __syncthreads();

  // ---- sweep: acc[rr][s] covers j = s*2048 + 4*tid .. +3 ----
  const float4* hT4 = reinterpret_cast<const float4*>(hT);
  float4 acc[NROW][2];
#pragma unroll
  for (int rr = 0; rr < NROW; rr++)
#pragma unroll
    for (int s = 0; s < 2; s++) acc[rr][s] = make_float4(0.f, 0.f, 0.f, 0.f);

#pragma unroll 4
  for (int c = 0; c < FI; c++) {
    float4 v0 = hT4[c * 1024 + tid];
    float4 v1 = hT4[c * 1024 + 512 + tid];
#pragma unroll
    for (int rr = 0; rr < NROW; rr++) {
      float hc = hi[rr][c];
      acc[rr][0].x += hc * v0.x; acc[rr][0].y += hc * v0.y;
      acc[rr][0].z += hc * v0.z; acc[rr][0].w += hc * v0.w;
      acc[rr][1].x += hc * v1.x; acc[rr][1].y += hc * v1.y;
      acc[rr][1].z += hc * v1.z; acc[rr][1].w += hc * v1.w;
    }
  }

  // ---- finalize to monotonic-mapped u32 keys (exact reference formula) ----
  const float4* sq4p = reinterpret_cast<const float4*>(sq);
  const float4* mask4 = reinterpret_cast<const float4*>(mask);
  u32 key[NROW][8];
#pragma unroll
  for (int s = 0; s < 2; s++) {
    float4 sq4 = sq4p[s * 512 + tid];
    int jb = s * 2048 + 4 * tid;
#pragma unroll
    for (int rr = 0; rr < NROW; rr++) {
      int row = r0 + rr;
      float4 m4 = mask4[(size_t)row * 1024 + s * 512 + tid];
      float sqr = sqi4[rr];
      float d0 = fabsf(sqr + sq4.x - 2.f * acc[rr][s].x) * m4.x;
      float d1 = fabsf(sqr + sq4.y - 2.f * acc[rr][s].y) * m4.y;
      float d2 = fabsf(sqr + sq4.z - 2.f * acc[rr][s].z) * m4.z;
      float d3 = fabsf(sqr + sq4.w - 2.f * acc[rr][s].w) * m4.w;
      d0 -= (jb + 0 == row) ? 2.f : 0.f;
      d1 -= (jb + 1 == row) ? 2.f : 0.f;
      d2 -= (jb + 2 == row) ? 2.f : 0.f;
      d3 -= (jb + 3 == row) ? 2.f : 0.f;
      u32 u0 = __float_as_uint(d0); u0 ^= (u32)((int)u0 >> 31) | 0x80000000u;
      u32 u1 = __float_as_uint(d1); u1 ^= (u32)((int)u1 >> 31) | 0x80000000u;
      u32 u2 = __float_as_uint(d2); u2 ^= (u32)((int)u2 >> 31) | 0x80000000u;
      u32 u3 = __float_as_uint(d3); u3 ^= (u32)((int)u3 >> 31) | 0x80000000u;
      key[rr][s * 4 + 0] = u0; key[rr][s * 4 + 1] = u1;
      key[rr][s * 4 + 2] = u2; key[rr][s * 4 + 3] = u3;
    }
  }

  // ---- per-thread minima ----
#pragma unroll
  for (int rr = 0; rr < NROW; rr++) {
    u32 m = key[rr][0];
#pragma unroll
    for (int i = 1; i < 8; i++) m = key[rr][i] < m ? key[rr][i] : m;
    lmin[rr][tid] = m;
  }
  __syncthreads();

  const int w = tid >> 6, lane = tid & 63;

  // ---- threshold: waves 0..3, T[w] = 25th smallest of 64 group-minima ----
  if (w < NROW) {
    u32 g = lmin[w][lane];
#pragma unroll
    for (int k = 1; k < 8; k++) {
      u32 x = lmin[w][64 * k + lane];
      g = x < g ? x : g;
    }
#pragma unroll
    for (int kk = 2; kk <= 64; kk <<= 1)
#pragma unroll
      for (int jj = kk >> 1; jj > 0; jj >>= 1) {
        u32 o = __shfl_xor(g, jj, 64);
        bool low = (lane & jj) == 0, asc = (lane & kk) == 0;
        u32 mn = o < g ? o : g, mx = o < g ? g : o;
        g = (low == asc) ? mn : mx;
      }
    if (lane == 24) Tsh[w] = g;
  }
  __syncthreads();

  // ---- compaction: keys <= T[r] -> cbuf ----
#pragma unroll
  for (int rr = 0; rr < NROW; rr++) {
    u32 Tr = Tsh[rr];
#pragma unroll
    for (int s = 0; s < 2; s++)
#pragma unroll
      for (int i = 0; i < 4; i++) {
        u32 kv = key[rr][s * 4 + i];
        if (kv <= Tr) {
          int p = atomicAdd(&cnts[rr], 1);
          if (p < 128) cbuf[rr][p] = ((u64)kv << 12) | (u64)(s * 2048 + 4 * tid + i);
        }
      }
  }
  __syncthreads();

  // ---- waves 0..3: 128-wide bitonic sort of row w's candidates ----
  if (w < NROW) {
    const u64 UMAX = ~0ull;
    int cnt = cnts[w];
    u64 v0 = (lane < cnt) ? cbuf[w][lane] : UMAX;
    u64 v1 = (64 + lane < cnt) ? cbuf[w][64 + lane] : UMAX;
#pragma unroll
    for (int kk = 2; kk <= 128; kk <<= 1) {
#pragma unroll
      for (int jj = kk >> 1; jj > 0; jj >>= 1) {
        if (jj >= 64) {
          bool asc = (lane & kk) == 0;
          u64 mn = v0 < v1 ? v0 : v1, mx = v0 < v1 ? v1 : v0;
          v0 = asc ? mn : mx; v1 = asc ? mx : mn;
        } else {
          bool low = (lane & jj) == 0;
          bool asc0 = (lane & kk) == 0;
          bool asc1 = ((64 + lane) & kk) == 0;
          u64 o0 = __shfl_xor(v0, jj, 64);
          v0 = (low == asc0) ? (o0 < v0 ? o0 : v0) : (o0 < v0 ? v0 : o0);
          u64 o1 = __shfl_xor(v1, jj, 64);
          v1 = (low == asc1) ? (o1 < v1 ? o1 : v1) : (o1 < v1 ? v1 : o1);
        }
      }
    }
    int row = r0 + w;
    int idx = (int)(v0 & 4095ull);
    if (lane == 0) ctr_idx[row] = idx;
    if (lane >= 9 && lane < NSEL) nbr_idx[row * KNN + (lane - 9)] = idx;
  }
}

// ---------------- K3: P1e[n][m] = dot44(h[n], Wr[m]) ----------------
// m = r*44+c (m<484): Wr[m] = W1[c, r*44 .. r*44+43]; m=484+r: b1[r]; m=495: 0.
__global__ __launch_bounds__(256) void k_P1(const float* __restrict__ h,
                                            const float* __restrict__ W1,
                                            const float* __restrict__ b1,
                                            float* __restrict__ P1e) {
  __shared__ __align__(16) float Wr[ME][FI];   // 87.3 KB
  const int tid = threadIdx.x;
  for (int t = tid; t < 484 * 11; t += 256) {
    int m = t / 11, k4 = t % 11;
    int r = m / FI, c = m % FI;
    float4 wv = *reinterpret_cast<const float4*>(W1 + (size_t)c * 484 + r * FI + 4 * k4);
    *reinterpret_cast<float4*>(&Wr[m][4 * k4]) = wv;
  }
  for (int t = tid; t < 11 * 11; t += 256) {
    int r = t / 11, k4 = t % 11;
    float4 wv = *reinterpret_cast<const float4*>(b1 + r * FI + 4 * k4);
    *reinterpret_cast<float4*>(&Wr[484 + r][4 * k4]) = wv;
  }
  if (tid < 11) *reinterpret_cast<float4*>(&Wr[495][4 * tid]) = make_float4(0.f, 0.f, 0.f, 0.f);
  __syncthreads();

  const int n = blockIdx.x * 64 + (tid >> 2);
  const int g = tid & 3;
  float4 hreg[11];
  const float4* hr = reinterpret_cast<const float4*>(h + (size_t)n * FI);
#pragma unroll
  for (int k4 = 0; k4 < 11; k4++) hreg[k4] = hr[k4];

  for (int mi = 0; mi < 124; mi++) {
    int m = g + 4 * mi;
    float acc = 0.f;
#pragma unroll
    for (int k4 = 0; k4 < 11; k4++) {
      float4 wv = *reinterpret_cast<const float4*>(&Wr[m][4 * k4]);
      acc += wv.x*hreg[k4].x + wv.y*hreg[k4].y + wv.z*hreg[k4].z + wv.w*hreg[k4].w;
    }
    P1e[(size_t)n * ME + m] = acc;
  }
}

// ---------------- K4: fused lab + t' + G (block = 4 nodes, 64 edges) ----------------
__global__ __launch_bounds__(256) void k_edge(
    const float* __restrict__ h,
    const int* __restrict__ ctr_idx, const int* __restrict__ nbr_idx,
    const float* __restrict__ W_lab, const float* __restrict__ b_lab,
    const float* __restrict__ Wl, const float* __restrict__ bl,
    const float* __restrict__ P1e,
    float* __restrict__ Ge)
{
  __shared__ __align__(16) float WlabT[FI][FI];   // [f][c]  7.7 KB
  __shared__ __align__(16) float lbl[64][FI];     // labels, then lab in-place
  __shared__ float WlT[RK][FI];                   // [r][c]
  __shared__ float tfs[64][12];                   // t' (wexp folded)
  __shared__ float wexpS[64];
  __shared__ int nbrL[64];
  __shared__ int ctrL[4];
  const int tid = threadIdx.x;
  const int b = blockIdx.x;

  if (tid < 64) nbrL[tid] = nbr_idx[b * 64 + tid];
  if (tid < 4) ctrL[tid] = ctr_idx[b * 4 + tid];
  for (int t = tid; t < FI * FI; t += 256) {
    int c = t / FI, f = t % FI;
    WlabT[f][c] = W_lab[t];
  }
  for (int t = tid; t < FI * RK; t += 256) {
    int c = t / RK, r = t % RK;
    WlT[r][c] = Wl[t];
  }
  __syncthreads();

  for (int t = tid; t < 64 * FI; t += 256) {
    int e = t / FI, c = t % FI;
    lbl[e][c] = h[(size_t)nbrL[e] * FI + c] - h[(size_t)ctrL[e >> 4] * FI + c];
  }
  __syncthreads();

  // wexp from ||labels||^2
  if (tid < 64) {
    float s = 0.f;
#pragma unroll
    for (int c4 = 0; c4 < 11; c4++) {
      float4 v = *reinterpret_cast<const float4*>(&lbl[tid][4 * c4]);
      s += v.x*v.x + v.y*v.y + v.z*v.z + v.w*v.w;
    }
    wexpS[tid] = expf(-s * 0.1f) * (1.0f / 16.0f);
  }

  // lab = leaky_relu(labels @ W_lab + b_lab), computed to regs then in-place
  const int e = tid >> 2;      // edge 0..63
  const int g = tid & 3;
  float la[11];
#pragma unroll
  for (int u = 0; u < 11; u++) {
    int f = g + 4 * u;
    float acc = b_lab[f];
#pragma unroll
    for (int c4 = 0; c4 < 11; c4++) {
      float4 wv = *reinterpret_cast<const float4*>(&WlabT[f][4 * c4]);
      float4 lv = *reinterpret_cast<const float4*>(&lbl[e][4 * c4]);
      acc += wv.x*lv.x + wv.y*lv.y + wv.z*lv.z + wv.w*lv.w;
    }
    la[u] = acc >= 0.f ? acc : 0.2f * acc;
  }
  __syncthreads();             // all labels reads (incl. wexp) done
#pragma unroll
  for (int u = 0; u < 11; u++) lbl[e][g + 4 * u] = la[u];
  __syncthreads();             // lab ready

  // t'[e][r] = wexp * (dot_c(lab, P1[n1, r*44+c]) + P1[n1,484+r]) * (lab@WlT[r] + bl[r])
  const int l16 = tid & 15;
  const int eL = tid >> 4;     // 0..15
  for (int e4 = 0; e4 < 4; e4++) {
    int ee = e4 * 16 + eL;
    const float* P1r = P1e + (size_t)nbrL[ee] * ME;
    float labv[3];
#pragma unroll
    for (int m = 0; m < 3; m++) {
      int c = l16 + 16 * m;
      labv[m] = (c < FI) ? lbl[ee][c] : 0.f;
    }
    for (int r = 0; r < RK; r++) {
      float tp = 0.f, tlp = 0.f;
#pragma unroll
      for (int m = 0; m < 3; m++) {
        int c = l16 + 16 * m;
        if (c < FI) {
          tp += labv[m] * P1r[r * FI + c];
          tlp += labv[m] * WlT[r][c];
        }
      }
#pragma unroll
      for (int off = 1; off < 16; off <<= 1) {
        tp += __shfl_xor(tp, off, 64);
        tlp += __shfl_xor(tlp, off, 64);
      }
      if (l16 == r)
        tfs[ee][r] = (tp + P1r[484 + r]) * (tlp + bl[r]) * wexpS[ee];
    }
  }
  __syncthreads();

  // G: Ge[n][r*44+c] = sum_k lab[e,c]*t'[e,r]; Ge[n][484+r] = sum_k t'[e,r]
  const int nn = tid >> 6, lane = tid & 63;
  const int n = b * 4 + nn;
  if (lane < FI) {
    float acc2[RK];
#pragma unroll
    for (int r = 0; r < RK; r++) acc2[r] = 0.f;
    for (int k = 0; k < KNN; k++) {
      float lv = lbl[nn * 16 + k][lane];
#pragma unroll
      for (int r = 0; r < RK; r++) acc2[r] += lv * tfs[nn * 16 + k][r];
    }
#pragma unroll
    for (int r = 0; r < RK; r++) Ge[(size_t)n * ME + r * FI + lane] = acc2[r];
  } else if (lane < FI + RK) {
    int r = lane - FI;
    float ss = 0.f;
    for (int k = 0; k < KNN; k++) ss += tfs[nn * 16 + k][r];
    Ge[(size_t)n * ME + 484 + r] = ss;
  } else if (lane == 55) {
    Ge[(size_t)n * ME + 495] = 0.f;
  }
}

// ---------------- K5: out[n][fo] = sum_m Ge[n][m] * W2eT[fo][m] ----------------
__global__ __launch_bounds__(256) void k_out(const float* __restrict__ Ge,
                                             const float* __restrict__ W2,
                                             const float* __restrict__ b2,
                                             float* __restrict__ out) {
  __shared__ __align__(16) float W2eT[FI][ME];   // 87.3 KB
  const int tid = threadIdx.x;
  for (int t = tid; t < 484 * 11; t += 256) {
    int m = t / 11, k4 = t % 11;
    int r = m / FI, c = m % FI;
    float4 wv = *reinterpret_cast<const float4*>(W2 + (size_t)c * 484 + r * FI + 4 * k4);
    W2eT[4*k4+0][m] = wv.x; W2eT[4*k4+1][m] = wv.y; W2eT[4*k4+2][m] = wv.z; W2eT[4*k4+3][m] = wv.w;
  }
  for (int t = tid; t < 11 * 11; t += 256) {
    int r = t / 11, k4 = t % 11;
    float4 wv = *reinterpret_cast<const float4*>(b2 + r * FI + 4 * k4);
    W2eT[4*k4+0][484+r] = wv.x; W2eT[4*k4+1][484+r] = wv.y; W2eT[4*k4+2][484+r] = wv.z; W2eT[4*k4+3][484+r] = wv.w;
  }
  if (tid < FI) W2eT[tid][495] = 0.f;
  __syncthreads();

  const int n = blockIdx.x * 64 + (tid >> 2);
  const int g = tid & 3;
  const float4* gr = reinterpret_cast<const float4*>(Ge + (size_t)n * ME);
  float acc[11];
#pragma unroll
  for (int u = 0; u < 11; u++) acc[u] = 0.f;
  for (int mc = 0; mc < ME / 4; mc++) {
    float4 g4 = gr[mc];
#pragma unroll
    for (int u = 0; u < 11; u++) {
      int fo = g + 4 * u;
      float4 w4 = *reinterpret_cast<const float4*>(&W2eT[fo][4 * mc]);
      acc[u] += g4.x*w4.x + g4.y*w4.y + g4.z*w4.z + g4.w*w4.w;
    }
  }
#pragma unroll
  for (int u = 0; u < 11; u++) out[(size_t)n * FI + g + 4 * u] = acc[u];
}

extern "C" void kernel_launch(void* const* d_in, const int* in_sizes, int n_in,
                              void* d_out, int out_size, void* d_ws, size_t ws_size,
                              hipStream_t stream) {
  const float* h     = (const float*)d_in[0];
  const float* mask  = (const float*)d_in[1];
  const float* W_lab = (const float*)d_in[2];
  const float* b_lab = (const float*)d_in[3];
  const float* W1    = (const float*)d_in[4];
  const float* b1    = (const float*)d_in[5];
  const float* W2    = (const float*)d_in[6];
  const float* b2    = (const float*)d_in[7];
  const float* Wl    = (const float*)d_in[8];
  const float* bl    = (const float*)d_in[9];

  float* sqw  = (float*)d_ws;                       // [4096]
  float* hT   = sqw + N;                            // [44*4096]
  int*   ctr  = (int*)(hT + (size_t)FI * N);        // [4096]
  int*   nbr  = ctr + N;                            // [65536]
  float* P1e  = (float*)(nbr + N * KNN);            // [4096*496]
  float* Ge   = P1e + (size_t)N * ME;               // [4096*496]

  k_prep<<<N / 256, 256, 0, stream>>>(h, sqw, hT);
  k_dist_topk<<<N / NROW, 512, 0, stream>>>(hT, sqw, mask, ctr, nbr);
  k_P1<<<N / 64, 256, 0, stream>>>(h, W1, b1, P1e);
  k_edge<<<N * KNN / 64, 256, 0, stream>>>(h, ctr, nbr, W_lab, b_lab, Wl, bl, P1e, Ge);
  k_out<<<N / 64, 256, 0, stream>>>(Ge, W2, b2, (float*)d_out);
}

// Round 7
// 148.770 us; speedup vs baseline: 17.3161x; 1.1790x over previous
//
#include <hip/hip_runtime.h>
#include <float.h>

#define N 4096
#define FI 44
#define RK 11
#define KNN 16
#define NSEL 25   // K + 9 ranks kept
#define NROW 4
#define ME 496    // padded reduction dim: 484 (c,r) + 11 bias + 1 pad

typedef unsigned long long u64;
typedef unsigned int u32;

// ---------------- K0: sq norms + h transpose ----------------
__global__ __launch_bounds__(256) void k_prep(const float* __restrict__ h,
                                              float* __restrict__ sq,
                                              float* __restrict__ hT) {
  int n = blockIdx.x * 256 + threadIdx.x;
  const float4* hr = reinterpret_cast<const float4*>(h + (size_t)n * FI);
  float v[FI];
  float s = 0.f;
#pragma unroll
  for (int c4 = 0; c4 < 11; c4++) {
    float4 x = hr[c4];
    v[4*c4] = x.x; v[4*c4+1] = x.y; v[4*c4+2] = x.z; v[4*c4+3] = x.w;
    s += x.x*x.x + x.y*x.y + x.z*x.z + x.w*x.w;
  }
  sq[n] = s;
#pragma unroll
  for (int c = 0; c < FI; c++) hT[c * N + n] = v[c];   // coalesced per c
}

// ---------------- K2: distance rows + top-25, float4 sweep ----------------
// 512 threads; thread owns j in {4*tid+i} and {2048+4*tid+i} (i<4) for 4 rows.
// mask/sq prefetched to registers BEFORE the sweep so HBM latency hides under
// the 1408 FMAs. Threshold T[r] = 25th smallest of 64 group-minima => >=25
// keys <= T. Compact u64 (value<<12|col), 128-wide bitonic sort per row gives
// exact jax.lax.top_k order (value asc, then smaller index).
__global__ __launch_bounds__(512) void k_dist_topk(const float* __restrict__ hT,
                                                   const float* __restrict__ sq,
                                                   const float* __restrict__ mask,
                                                   int* __restrict__ ctr_idx,
                                                   int* __restrict__ nbr_idx) {
  __shared__ __align__(16) float hi[NROW][FI];
  __shared__ float sqi4[NROW];
  __shared__ u32 lmin[NROW][512];     // 8 KB
  __shared__ u32 Tsh[NROW];
  __shared__ int cnts[NROW];
  __shared__ u64 cbuf[NROW][128];     // 4 KB
  const int tid = threadIdx.x;
  const int r0 = blockIdx.x * NROW;

  if (tid < NROW) { cnts[tid] = 0; sqi4[tid] = sq[r0 + tid]; }
  for (int t = tid; t < NROW * FI; t += 512) {
    int rr = t / FI, c = t % FI;
    hi[rr][c] = hT[c * N + (r0 + rr)];
  }
  __syncthreads();

  // ---- prefetch mask + sq for this thread's 8 columns (HBM/L3 latency
  //      hides under the sweep below) ----
  const float4* sq4p = reinterpret_cast<const float4*>(sq);
  const float4* mask4 = reinterpret_cast<const float4*>(mask);
  float4 m4r[2][NROW];
  float4 sq4r[2];
#pragma unroll
  for (int s = 0; s < 2; s++) {
    sq4r[s] = sq4p[s * 512 + tid];
#pragma unroll
    for (int rr = 0; rr < NROW; rr++)
      m4r[s][rr] = mask4[(size_t)(r0 + rr) * 1024 + s * 512 + tid];
  }

  // ---- sweep: acc[rr][s] covers j = s*2048 + 4*tid .. +3 ----
  const float4* hT4 = reinterpret_cast<const float4*>(hT);
  float4 acc[NROW][2];
#pragma unroll
  for (int rr = 0; rr < NROW; rr++)
#pragma unroll
    for (int s = 0; s < 2; s++) acc[rr][s] = make_float4(0.f, 0.f, 0.f, 0.f);

#pragma unroll 4
  for (int c = 0; c < FI; c++) {
    float4 v0 = hT4[c * 1024 + tid];
    float4 v1 = hT4[c * 1024 + 512 + tid];
#pragma unroll
    for (int rr = 0; rr < NROW; rr++) {
      float hc = hi[rr][c];
      acc[rr][0].x += hc * v0.x; acc[rr][0].y += hc * v0.y;
      acc[rr][0].z += hc * v0.z; acc[rr][0].w += hc * v0.w;
      acc[rr][1].x += hc * v1.x; acc[rr][1].y += hc * v1.y;
      acc[rr][1].z += hc * v1.z; acc[rr][1].w += hc * v1.w;
    }
  }

  // ---- finalize to monotonic-mapped u32 keys (exact reference formula) ----
  u32 key[NROW][8];
#pragma unroll
  for (int s = 0; s < 2; s++) {
    float4 sq4 = sq4r[s];
    int jb = s * 2048 + 4 * tid;
#pragma unroll
    for (int rr = 0; rr < NROW; rr++) {
      int row = r0 + rr;
      float4 m4 = m4r[s][rr];
      float sqr = sqi4[rr];
      float d0 = fabsf(sqr + sq4.x - 2.f * acc[rr][s].x) * m4.x;
      float d1 = fabsf(sqr + sq4.y - 2.f * acc[rr][s].y) * m4.y;
      float d2 = fabsf(sqr + sq4.z - 2.f * acc[rr][s].z) * m4.z;
      float d3 = fabsf(sqr + sq4.w - 2.f * acc[rr][s].w) * m4.w;
      d0 -= (jb + 0 == row) ? 2.f : 0.f;
      d1 -= (jb + 1 == row) ? 2.f : 0.f;
      d2 -= (jb + 2 == row) ? 2.f : 0.f;
      d3 -= (jb + 3 == row) ? 2.f : 0.f;
      u32 u0 = __float_as_uint(d0); u0 ^= (u32)((int)u0 >> 31) | 0x80000000u;
      u32 u1 = __float_as_uint(d1); u1 ^= (u32)((int)u1 >> 31) | 0x80000000u;
      u32 u2 = __float_as_uint(d2); u2 ^= (u32)((int)u2 >> 31) | 0x80000000u;
      u32 u3 = __float_as_uint(d3); u3 ^= (u32)((int)u3 >> 31) | 0x80000000u;
      key[rr][s * 4 + 0] = u0; key[rr][s * 4 + 1] = u1;
      key[rr][s * 4 + 2] = u2; key[rr][s * 4 + 3] = u3;
    }
  }

  // ---- per-thread minima ----
#pragma unroll
  for (int rr = 0; rr < NROW; rr++) {
    u32 m = key[rr][0];
#pragma unroll
    for (int i = 1; i < 8; i++) m = key[rr][i] < m ? key[rr][i] : m;
    lmin[rr][tid] = m;
  }
  __syncthreads();

  const int w = tid >> 6, lane = tid & 63;

  // ---- threshold: waves 0..3, T[w] = 25th smallest of 64 group-minima ----
  if (w < NROW) {
    u32 g = lmin[w][lane];
#pragma unroll
    for (int k = 1; k < 8; k++) {
      u32 x = lmin[w][64 * k + lane];
      g = x < g ? x : g;
    }
#pragma unroll
    for (int kk = 2; kk <= 64; kk <<= 1)
#pragma unroll
      for (int jj = kk >> 1; jj > 0; jj >>= 1) {
        u32 o = __shfl_xor(g, jj, 64);
        bool low = (lane & jj) == 0, asc = (lane & kk) == 0;
        u32 mn = o < g ? o : g, mx = o < g ? g : o;
        g = (low == asc) ? mn : mx;
      }
    if (lane == 24) Tsh[w] = g;
  }
  __syncthreads();

  // ---- compaction: keys <= T[r] -> cbuf ----
#pragma unroll
  for (int rr = 0; rr < NROW; rr++) {
    u32 Tr = Tsh[rr];
#pragma unroll
    for (int s = 0; s < 2; s++)
#pragma unroll
      for (int i = 0; i < 4; i++) {
        u32 kv = key[rr][s * 4 + i];
        if (kv <= Tr) {
          int p = atomicAdd(&cnts[rr], 1);
          if (p < 128) cbuf[rr][p] = ((u64)kv << 12) | (u64)(s * 2048 + 4 * tid + i);
        }
      }
  }
  __syncthreads();

  // ---- waves 0..3: 128-wide bitonic sort of row w's candidates ----
  if (w < NROW) {
    const u64 UMAX = ~0ull;
    int cnt = cnts[w];
    u64 v0 = (lane < cnt) ? cbuf[w][lane] : UMAX;
    u64 v1 = (64 + lane < cnt) ? cbuf[w][64 + lane] : UMAX;
#pragma unroll
    for (int kk = 2; kk <= 128; kk <<= 1) {
#pragma unroll
      for (int jj = kk >> 1; jj > 0; jj >>= 1) {
        if (jj >= 64) {
          bool asc = (lane & kk) == 0;
          u64 mn = v0 < v1 ? v0 : v1, mx = v0 < v1 ? v1 : v0;
          v0 = asc ? mn : mx; v1 = asc ? mx : mn;
        } else {
          bool low = (lane & jj) == 0;
          bool asc0 = (lane & kk) == 0;
          bool asc1 = ((64 + lane) & kk) == 0;
          u64 o0 = __shfl_xor(v0, jj, 64);
          v0 = (low == asc0) ? (o0 < v0 ? o0 : v0) : (o0 < v0 ? v0 : o0);
          u64 o1 = __shfl_xor(v1, jj, 64);
          v1 = (low == asc1) ? (o1 < v1 ? o1 : v1) : (o1 < v1 ? v1 : o1);
        }
      }
    }
    int row = r0 + w;
    int idx = (int)(v0 & 4095ull);
    if (lane == 0) ctr_idx[row] = idx;
    if (lane >= 9 && lane < NSEL) nbr_idx[row * KNN + (lane - 9)] = idx;
  }
}

// ---------------- K3: P1e[n][m] = dot44(h[n], Wr[m]) ----------------
// m = r*44+c (m<484): Wr[m] = W1[c, r*44 .. r*44+43]; m=484+r: b1[r]; m=495: 0.
__global__ __launch_bounds__(256) void k_P1(const float* __restrict__ h,
                                            const float* __restrict__ W1,
                                            const float* __restrict__ b1,
                                            float* __restrict__ P1e) {
  __shared__ __align__(16) float Wr[ME][FI];   // 87.3 KB
  const int tid = threadIdx.x;
  for (int t = tid; t < 484 * 11; t += 256) {
    int m = t / 11, k4 = t % 11;
    int r = m / FI, c = m % FI;
    float4 wv = *reinterpret_cast<const float4*>(W1 + (size_t)c * 484 + r * FI + 4 * k4);
    *reinterpret_cast<float4*>(&Wr[m][4 * k4]) = wv;
  }
  for (int t = tid; t < 11 * 11; t += 256) {
    int r = t / 11, k4 = t % 11;
    float4 wv = *reinterpret_cast<const float4*>(b1 + r * FI + 4 * k4);
    *reinterpret_cast<float4*>(&Wr[484 + r][4 * k4]) = wv;
  }
  if (tid < 11) *reinterpret_cast<float4*>(&Wr[495][4 * tid]) = make_float4(0.f, 0.f, 0.f, 0.f);
  __syncthreads();

  const int n = blockIdx.x * 64 + (tid >> 2);
  const int g = tid & 3;
  float4 hreg[11];
  const float4* hr = reinterpret_cast<const float4*>(h + (size_t)n * FI);
#pragma unroll
  for (int k4 = 0; k4 < 11; k4++) hreg[k4] = hr[k4];

  for (int mi = 0; mi < 124; mi++) {
    int m = g + 4 * mi;
    float acc = 0.f;
#pragma unroll
    for (int k4 = 0; k4 < 11; k4++) {
      float4 wv = *reinterpret_cast<const float4*>(&Wr[m][4 * k4]);
      acc += wv.x*hreg[k4].x + wv.y*hreg[k4].y + wv.z*hreg[k4].z + wv.w*hreg[k4].w;
    }
    P1e[(size_t)n * ME + m] = acc;
  }
}

// ---------------- K4: fused lab + t' + G (block = 4 nodes, 64 edges) ----------------
// t' phase: 4 lanes per edge, lane g owns r in {g, g+4, g+8}; full 44-MAC dot
// in registers, P1 read as aligned float4 (44 floats = 11 x 16B). No shuffles.
__global__ __launch_bounds__(256) void k_edge(
    const float* __restrict__ h,
    const int* __restrict__ ctr_idx, const int* __restrict__ nbr_idx,
    const float* __restrict__ W_lab, const float* __restrict__ b_lab,
    const float* __restrict__ Wl, const float* __restrict__ bl,
    const float* __restrict__ P1e,
    float* __restrict__ Ge)
{
  __shared__ __align__(16) float WlabT[FI][FI];   // [f][c]  7.7 KB
  __shared__ __align__(16) float lbl[64][FI];     // labels, then lab in-place
  __shared__ __align__(16) float WlT[RK][FI];     // [r][c]
  __shared__ float blS[RK];
  __shared__ float tfs[64][12];                   // t' (wexp folded)
  __shared__ float wexpS[64];
  __shared__ int nbrL[64];
  __shared__ int ctrL[4];
  const int tid = threadIdx.x;
  const int b = blockIdx.x;

  if (tid < 64) nbrL[tid] = nbr_idx[b * 64 + tid];
  if (tid < 4) ctrL[tid] = ctr_idx[b * 4 + tid];
  if (tid < RK) blS[tid] = bl[tid];
  for (int t = tid; t < FI * FI; t += 256) {
    int c = t / FI, f = t % FI;
    WlabT[f][c] = W_lab[t];
  }
  for (int t = tid; t < FI * RK; t += 256) {
    int c = t / RK, r = t % RK;
    WlT[r][c] = Wl[t];
  }
  __syncthreads();

  for (int t = tid; t < 64 * FI; t += 256) {
    int e = t / FI, c = t % FI;
    lbl[e][c] = h[(size_t)nbrL[e] * FI + c] - h[(size_t)ctrL[e >> 4] * FI + c];
  }
  __syncthreads();

  // wexp from ||labels||^2
  if (tid < 64) {
    float s = 0.f;
#pragma unroll
    for (int c4 = 0; c4 < 11; c4++) {
      float4 v = *reinterpret_cast<const float4*>(&lbl[tid][4 * c4]);
      s += v.x*v.x + v.y*v.y + v.z*v.z + v.w*v.w;
    }
    wexpS[tid] = expf(-s * 0.1f) * (1.0f / 16.0f);
  }

  // lab = leaky_relu(labels @ W_lab + b_lab), regs then in-place
  const int e = tid >> 2;      // edge 0..63
  const int g = tid & 3;
  float la[11];
#pragma unroll
  for (int u = 0; u < 11; u++) {
    int f = g + 4 * u;
    float acc = b_lab[f];
#pragma unroll
    for (int c4 = 0; c4 < 11; c4++) {
      float4 wv = *reinterpret_cast<const float4*>(&WlabT[f][4 * c4]);
      float4 lv = *reinterpret_cast<const float4*>(&lbl[e][4 * c4]);
      acc += wv.x*lv.x + wv.y*lv.y + wv.z*lv.z + wv.w*lv.w;
    }
    la[u] = acc >= 0.f ? acc : 0.2f * acc;
  }
  __syncthreads();             // all labels reads (incl. wexp) done
#pragma unroll
  for (int u = 0; u < 11; u++) lbl[e][g + 4 * u] = la[u];
  __syncthreads();             // lab ready

  // ---- t'[e][r] = wexp * (dot_c(lab, P1[n1][r*44+c]) + P1[n1][484+r])
  //                      * (dot_c(lab, WlT[r]) + bl[r]) ----
  {
    float4 labr[11];
#pragma unroll
    for (int c4 = 0; c4 < 11; c4++)
      labr[c4] = *reinterpret_cast<const float4*>(&lbl[e][4 * c4]);
    const float* P1r = P1e + (size_t)nbrL[e] * ME;
    float wex = wexpS[e];
#pragma unroll
    for (int rr = 0; rr < 3; rr++) {
      int r = g + 4 * rr;
      if (r < RK) {
        float tp = 0.f, tlp = 0.f;
#pragma unroll
        for (int c4 = 0; c4 < 11; c4++) {
          float4 p4 = *reinterpret_cast<const float4*>(P1r + r * FI + 4 * c4);
          float4 w4 = *reinterpret_cast<const float4*>(&WlT[r][4 * c4]);
          float4 l4 = labr[c4];
          tp  += l4.x*p4.x + l4.y*p4.y + l4.z*p4.z + l4.w*p4.w;
          tlp += l4.x*w4.x + l4.y*w4.y + l4.z*w4.z + l4.w*w4.w;
        }
        tfs[e][r] = (tp + P1r[484 + r]) * (tlp + blS[r]) * wex;
      }
    }
  }
  __syncthreads();

  // G: Ge[n][r*44+c] = sum_k lab[e,c]*t'[e,r]; Ge[n][484+r] = sum_k t'[e,r]
  const int nn = tid >> 6, lane = tid & 63;
  const int n = b * 4 + nn;
  if (lane < FI) {
    float acc2[RK];
#pragma unroll
    for (int r = 0; r < RK; r++) acc2[r] = 0.f;
    for (int k = 0; k < KNN; k++) {
      float lv = lbl[nn * 16 + k][lane];
#pragma unroll
      for (int r = 0; r < RK; r++) acc2[r] += lv * tfs[nn * 16 + k][r];
    }
#pragma unroll
    for (int r = 0; r < RK; r++) Ge[(size_t)n * ME + r * FI + lane] = acc2[r];
  } else if (lane < FI + RK) {
    int r = lane - FI;
    float ss = 0.f;
    for (int k = 0; k < KNN; k++) ss += tfs[nn * 16 + k][r];
    Ge[(size_t)n * ME + 484 + r] = ss;
  } else if (lane == 55) {
    Ge[(size_t)n * ME + 495] = 0.f;
  }
}

// ---------------- K5: out[n][fo] = sum_m Ge[n][m] * W2eT[fo][m] ----------------
__global__ __launch_bounds__(256) void k_out(const float* __restrict__ Ge,
                                             const float* __restrict__ W2,
                                             const float* __restrict__ b2,
                                             float* __restrict__ out) {
  __shared__ __align__(16) float W2eT[FI][ME];   // 87.3 KB
  const int tid = threadIdx.x;
  for (int t = tid; t < 484 * 11; t += 256) {
    int m = t / 11, k4 = t % 11;
    int r = m / FI, c = m % FI;
    float4 wv = *reinterpret_cast<const float4*>(W2 + (size_t)c * 484 + r * FI + 4 * k4);
    W2eT[4*k4+0][m] = wv.x; W2eT[4*k4+1][m] = wv.y; W2eT[4*k4+2][m] = wv.z; W2eT[4*k4+3][m] = wv.w;
  }
  for (int t = tid; t < 11 * 11; t += 256) {
    int r = t / 11, k4 = t % 11;
    float4 wv = *reinterpret_cast<const float4*>(b2 + r * FI + 4 * k4);
    W2eT[4*k4+0][484+r] = wv.x; W2eT[4*k4+1][484+r] = wv.y; W2eT[4*k4+2][484+r] = wv.z; W2eT[4*k4+3][484+r] = wv.w;
  }
  if (tid < FI) W2eT[tid][495] = 0.f;
  __syncthreads();

  const int n = blockIdx.x * 64 + (tid >> 2);
  const int g = tid & 3;
  const float4* gr = reinterpret_cast<const float4*>(Ge + (size_t)n * ME);
  float acc[11];
#pragma unroll
  for (int u = 0; u < 11; u++) acc[u] = 0.f;
  for (int mc = 0; mc < ME / 4; mc++) {
    float4 g4 = gr[mc];
#pragma unroll
    for (int u = 0; u < 11; u++) {
      int fo = g + 4 * u;
      float4 w4 = *reinterpret_cast<const float4*>(&W2eT[fo][4 * mc]);
      acc[u] += g4.x*w4.x + g4.y*w4.y + g4.z*w4.z + g4.w*w4.w;
    }
  }
#pragma unroll
  for (int u = 0; u < 11; u++) out[(size_t)n * FI + g + 4 * u] = acc[u];
}

extern "C" void kernel_launch(void* const* d_in, const int* in_sizes, int n_in,
                              void* d_out, int out_size, void* d_ws, size_t ws_size,
                              hipStream_t stream) {
  const float* h     = (const float*)d_in[0];
  const float* mask  = (const float*)d_in[1];
  const float* W_lab = (const float*)d_in[2];
  const float* b_lab = (const float*)d_in[3];
  const float* W1    = (const float*)d_in[4];
  const float* b1    = (const float*)d_in[5];
  const float* W2    = (const float*)d_in[6];
  const float* b2    = (const float*)d_in[7];
  const float* Wl    = (const float*)d_in[8];
  const float* bl    = (const float*)d_in[9];

  float* sqw  = (float*)d_ws;                       // [4096]
  float* hT   = sqw + N;                            // [44*4096]
  int*   ctr  = (int*)(hT + (size_t)FI * N);        // [4096]
  int*   nbr  = ctr + N;                            // [65536]
  float* P1e  = (float*)(nbr + N * KNN);            // [4096*496]
  float* Ge   = P1e + (size_t)N * ME;               // [4096*496]

  k_prep<<<N / 256, 256, 0, stream>>>(h, sqw, hT);
  k_dist_topk<<<N / NROW, 512, 0, stream>>>(hT, sqw, mask, ctr, nbr);
  k_P1<<<N / 64, 256, 0, stream>>>(h, W1, b1, P1e);
  k_edge<<<N * KNN / 64, 256, 0, stream>>>(h, ctr, nbr, W_lab, b_lab, Wl, bl, P1e, Ge);
  k_out<<<N / 64, 256, 0, stream>>>(Ge, W2, b2, (float*)d_out);
}

// Round 8
// 128.141 us; speedup vs baseline: 20.1039x; 1.1610x over previous
//
#include <hip/hip_runtime.h>
#include <float.h>

#define N 4096
#define FI 44
#define RK 11
#define KNN 16
#define NSEL 25   // K + 9 ranks kept
#define NROW 4
#define ME 496    // padded reduction dim: 484 (c,r) + 11 bias + 1 pad

typedef unsigned long long u64;
typedef unsigned int u32;

// ---------------- K0: sq norms + h transpose ----------------
__global__ __launch_bounds__(256) void k_prep(const float* __restrict__ h,
                                              float* __restrict__ sq,
                                              float* __restrict__ hT) {
  int n = blockIdx.x * 256 + threadIdx.x;
  const float4* hr = reinterpret_cast<const float4*>(h + (size_t)n * FI);
  float v[FI];
  float s = 0.f;
#pragma unroll
  for (int c4 = 0; c4 < 11; c4++) {
    float4 x = hr[c4];
    v[4*c4] = x.x; v[4*c4+1] = x.y; v[4*c4+2] = x.z; v[4*c4+3] = x.w;
    s += x.x*x.x + x.y*x.y + x.z*x.z + x.w*x.w;
  }
  sq[n] = s;
#pragma unroll
  for (int c = 0; c < FI; c++) hT[c * N + n] = v[c];   // coalesced per c
}

// ---------------- K1: weight pre-transpose (one-time) ----------------
// WrG[m][f]   (496x44): m=r*44+c -> W1[c][r*44+f]; m=484+r -> b1[r][f]; m=495 -> 0
// W2eTG[fo][m] (64x496): m=r*44+c -> W2[c][r*44+fo]; m=484+r -> b2[r][fo]; pad 0
__global__ __launch_bounds__(256) void k_wprep(const float* __restrict__ W1,
                                               const float* __restrict__ b1,
                                               const float* __restrict__ W2,
                                               const float* __restrict__ b2,
                                               float* __restrict__ WrG,
                                               float* __restrict__ W2eTG) {
  int idx0 = blockIdx.x * 256 + threadIdx.x;
  for (int idx = idx0; idx < 496 * FI; idx += gridDim.x * 256) {
    int m = idx / FI, f = idx - m * FI;
    float v;
    if (m < 484)      { int c = m % FI, r = m / FI; v = W1[c * 484 + r * FI + f]; }
    else if (m < 495) { int r = m - 484; v = b1[r * FI + f]; }
    else v = 0.f;
    WrG[idx] = v;
  }
  for (int idx = idx0; idx < 64 * ME; idx += gridDim.x * 256) {
    int fo = idx / ME, m = idx - fo * ME;
    float v = 0.f;
    if (fo < FI) {
      if (m < 484)      { int c = m % FI, r = m / FI; v = W2[c * 484 + r * FI + fo]; }
      else if (m < 495) { v = b2[(m - 484) * FI + fo]; }
    }
    W2eTG[idx] = v;
  }
}

// ---------------- K2: distance rows + top-25, float4 sweep ----------------
__global__ __launch_bounds__(512) void k_dist_topk(const float* __restrict__ hT,
                                                   const float* __restrict__ sq,
                                                   const float* __restrict__ mask,
                                                   int* __restrict__ ctr_idx,
                                                   int* __restrict__ nbr_idx) {
  __shared__ __align__(16) float hi[NROW][FI];
  __shared__ float sqi4[NROW];
  __shared__ u32 lmin[NROW][512];     // 8 KB
  __shared__ u32 Tsh[NROW];
  __shared__ int cnts[NROW];
  __shared__ u64 cbuf[NROW][128];     // 4 KB
  const int tid = threadIdx.x;
  const int r0 = blockIdx.x * NROW;

  if (tid < NROW) { cnts[tid] = 0; sqi4[tid] = sq[r0 + tid]; }
  for (int t = tid; t < NROW * FI; t += 512) {
    int rr = t / FI, c = t % FI;
    hi[rr][c] = hT[c * N + (r0 + rr)];
  }
  __syncthreads();

  // prefetch mask + sq (latency hides under sweep)
  const float4* sq4p = reinterpret_cast<const float4*>(sq);
  const float4* mask4 = reinterpret_cast<const float4*>(mask);
  float4 m4r[2][NROW];
  float4 sq4r[2];
#pragma unroll
  for (int s = 0; s < 2; s++) {
    sq4r[s] = sq4p[s * 512 + tid];
#pragma unroll
    for (int rr = 0; rr < NROW; rr++)
      m4r[s][rr] = mask4[(size_t)(r0 + rr) * 1024 + s * 512 + tid];
  }

  const float4* hT4 = reinterpret_cast<const float4*>(hT);
  float4 acc[NROW][2];
#pragma unroll
  for (int rr = 0; rr < NROW; rr++)
#pragma unroll
    for (int s = 0; s < 2; s++) acc[rr][s] = make_float4(0.f, 0.f, 0.f, 0.f);

#pragma unroll 4
  for (int c = 0; c < FI; c++) {
    float4 v0 = hT4[c * 1024 + tid];
    float4 v1 = hT4[c * 1024 + 512 + tid];
#pragma unroll
    for (int rr = 0; rr < NROW; rr++) {
      float hc = hi[rr][c];
      acc[rr][0].x += hc * v0.x; acc[rr][0].y += hc * v0.y;
      acc[rr][0].z += hc * v0.z; acc[rr][0].w += hc * v0.w;
      acc[rr][1].x += hc * v1.x; acc[rr][1].y += hc * v1.y;
      acc[rr][1].z += hc * v1.z; acc[rr][1].w += hc * v1.w;
    }
  }

  u32 key[NROW][8];
#pragma unroll
  for (int s = 0; s < 2; s++) {
    float4 sq4 = sq4r[s];
    int jb = s * 2048 + 4 * tid;
#pragma unroll
    for (int rr = 0; rr < NROW; rr++) {
      int row = r0 + rr;
      float4 m4 = m4r[s][rr];
      float sqr = sqi4[rr];
      float d0 = fabsf(sqr + sq4.x - 2.f * acc[rr][s].x) * m4.x;
      float d1 = fabsf(sqr + sq4.y - 2.f * acc[rr][s].y) * m4.y;
      float d2 = fabsf(sqr + sq4.z - 2.f * acc[rr][s].z) * m4.z;
      float d3 = fabsf(sqr + sq4.w - 2.f * acc[rr][s].w) * m4.w;
      d0 -= (jb + 0 == row) ? 2.f : 0.f;
      d1 -= (jb + 1 == row) ? 2.f : 0.f;
      d2 -= (jb + 2 == row) ? 2.f : 0.f;
      d3 -= (jb + 3 == row) ? 2.f : 0.f;
      u32 u0 = __float_as_uint(d0); u0 ^= (u32)((int)u0 >> 31) | 0x80000000u;
      u32 u1 = __float_as_uint(d1); u1 ^= (u32)((int)u1 >> 31) | 0x80000000u;
      u32 u2 = __float_as_uint(d2); u2 ^= (u32)((int)u2 >> 31) | 0x80000000u;
      u32 u3 = __float_as_uint(d3); u3 ^= (u32)((int)u3 >> 31) | 0x80000000u;
      key[rr][s * 4 + 0] = u0; key[rr][s * 4 + 1] = u1;
      key[rr][s * 4 + 2] = u2; key[rr][s * 4 + 3] = u3;
    }
  }

#pragma unroll
  for (int rr = 0; rr < NROW; rr++) {
    u32 m = key[rr][0];
#pragma unroll
    for (int i = 1; i < 8; i++) m = key[rr][i] < m ? key[rr][i] : m;
    lmin[rr][tid] = m;
  }
  __syncthreads();

  const int w = tid >> 6, lane = tid & 63;

  if (w < NROW) {
    u32 g = lmin[w][lane];
#pragma unroll
    for (int k = 1; k < 8; k++) {
      u32 x = lmin[w][64 * k + lane];
      g = x < g ? x : g;
    }
#pragma unroll
    for (int kk = 2; kk <= 64; kk <<= 1)
#pragma unroll
      for (int jj = kk >> 1; jj > 0; jj >>= 1) {
        u32 o = __shfl_xor(g, jj, 64);
        bool low = (lane & jj) == 0, asc = (lane & kk) == 0;
        u32 mn = o < g ? o : g, mx = o < g ? g : o;
        g = (low == asc) ? mn : mx;
      }
    if (lane == 24) Tsh[w] = g;
  }
  __syncthreads();

#pragma unroll
  for (int rr = 0; rr < NROW; rr++) {
    u32 Tr = Tsh[rr];
#pragma unroll
    for (int s = 0; s < 2; s++)
#pragma unroll
      for (int i = 0; i < 4; i++) {
        u32 kv = key[rr][s * 4 + i];
        if (kv <= Tr) {
          int p = atomicAdd(&cnts[rr], 1);
          if (p < 128) cbuf[rr][p] = ((u64)kv << 12) | (u64)(s * 2048 + 4 * tid + i);
        }
      }
  }
  __syncthreads();

  if (w < NROW) {
    const u64 UMAX = ~0ull;
    int cnt = cnts[w];
    u64 v0 = (lane < cnt) ? cbuf[w][lane] : UMAX;
    u64 v1 = (64 + lane < cnt) ? cbuf[w][64 + lane] : UMAX;
#pragma unroll
    for (int kk = 2; kk <= 128; kk <<= 1) {
#pragma unroll
      for (int jj = kk >> 1; jj > 0; jj >>= 1) {
        if (jj >= 64) {
          bool asc = (lane & kk) == 0;
          u64 mn = v0 < v1 ? v0 : v1, mx = v0 < v1 ? v1 : v0;
          v0 = asc ? mn : mx; v1 = asc ? mx : mn;
        } else {
          bool low = (lane & jj) == 0;
          bool asc0 = (lane & kk) == 0;
          bool asc1 = ((64 + lane) & kk) == 0;
          u64 o0 = __shfl_xor(v0, jj, 64);
          v0 = (low == asc0) ? (o0 < v0 ? o0 : v0) : (o0 < v0 ? v0 : o0);
          u64 o1 = __shfl_xor(v1, jj, 64);
          v1 = (low == asc1) ? (o1 < v1 ? o1 : v1) : (o1 < v1 ? v1 : o1);
        }
      }
    }
    int row = r0 + w;
    int idx = (int)(v0 & 4095ull);
    if (lane == 0) ctr_idx[row] = idx;
    if (lane >= 9 && lane < NSEL) nbr_idx[row * KNN + (lane - 9)] = idx;
  }
}

// ---------------- K3: P1e[n][m] = dot44(h[n], WrG[m]) — register-tiled ----------------
// 256 blocks x 256 thr; wave = 4 nodes in regs; lane owns m-columns. No LDS.
__global__ __launch_bounds__(256) void k_P1(const float* __restrict__ h,
                                            const float* __restrict__ WrG,
                                            float* __restrict__ P1e) {
  const int tid = threadIdx.x;
  const int grp = tid >> 6, lane = tid & 63;
  const int nb = blockIdx.x * 16 + grp * 4;
  const float4* h4 = reinterpret_cast<const float4*>(h);
  const float4* W4 = reinterpret_cast<const float4*>(WrG);

  float4 hq[4][11];
#pragma unroll
  for (int q = 0; q < 4; q++)
#pragma unroll
    for (int c4 = 0; c4 < 11; c4++)
      hq[q][c4] = h4[(size_t)(nb + q) * 11 + c4];

#pragma unroll
  for (int i = 0; i < 8; i++) {
    int m = lane + 64 * i;
    if (m < ME) {
      float a0 = 0.f, a1 = 0.f, a2 = 0.f, a3 = 0.f;
#pragma unroll
      for (int c4 = 0; c4 < 11; c4++) {
        float4 w = W4[m * 11 + c4];
        a0 += w.x*hq[0][c4].x + w.y*hq[0][c4].y + w.z*hq[0][c4].z + w.w*hq[0][c4].w;
        a1 += w.x*hq[1][c4].x + w.y*hq[1][c4].y + w.z*hq[1][c4].z + w.w*hq[1][c4].w;
        a2 += w.x*hq[2][c4].x + w.y*hq[2][c4].y + w.z*hq[2][c4].z + w.w*hq[2][c4].w;
        a3 += w.x*hq[3][c4].x + w.y*hq[3][c4].y + w.z*hq[3][c4].z + w.w*hq[3][c4].w;
      }
      P1e[(size_t)(nb + 0) * ME + m] = a0;
      P1e[(size_t)(nb + 1) * ME + m] = a1;
      P1e[(size_t)(nb + 2) * ME + m] = a2;
      P1e[(size_t)(nb + 3) * ME + m] = a3;
    }
  }
}

// ---------------- K4: fused lab + t' + G (block = 4 nodes, 64 edges) ----------------
__global__ __launch_bounds__(256) void k_edge(
    const float* __restrict__ h,
    const int* __restrict__ ctr_idx, const int* __restrict__ nbr_idx,
    const float* __restrict__ W_lab, const float* __restrict__ b_lab,
    const float* __restrict__ Wl, const float* __restrict__ bl,
    const float* __restrict__ P1e,
    float* __restrict__ Ge)
{
  __shared__ __align__(16) float WlabT[FI][FI];   // [f][c]  7.7 KB
  __shared__ __align__(16) float lbl[64][FI];     // labels, then lab in-place
  __shared__ __align__(16) float WlT[RK][FI];     // [r][c]
  __shared__ float blS[RK];
  __shared__ float tfs[64][12];                   // t' (wexp folded)
  __shared__ float wexpS[64];
  __shared__ int nbrL[64];
  __shared__ int ctrL[4];
  const int tid = threadIdx.x;
  const int b = blockIdx.x;

  if (tid < 64) nbrL[tid] = nbr_idx[b * 64 + tid];
  if (tid < 4) ctrL[tid] = ctr_idx[b * 4 + tid];
  if (tid < RK) blS[tid] = bl[tid];
  for (int t = tid; t < FI * FI; t += 256) {
    int c = t / FI, f = t % FI;
    WlabT[f][c] = W_lab[t];
  }
  for (int t = tid; t < FI * RK; t += 256) {
    int c = t / RK, r = t % RK;
    WlT[r][c] = Wl[t];
  }
  __syncthreads();

  for (int t = tid; t < 64 * FI; t += 256) {
    int e = t / FI, c = t % FI;
    lbl[e][c] = h[(size_t)nbrL[e] * FI + c] - h[(size_t)ctrL[e >> 4] * FI + c];
  }
  __syncthreads();

  if (tid < 64) {
    float s = 0.f;
#pragma unroll
    for (int c4 = 0; c4 < 11; c4++) {
      float4 v = *reinterpret_cast<const float4*>(&lbl[tid][4 * c4]);
      s += v.x*v.x + v.y*v.y + v.z*v.z + v.w*v.w;
    }
    wexpS[tid] = expf(-s * 0.1f) * (1.0f / 16.0f);
  }

  const int e = tid >> 2;      // edge 0..63
  const int g = tid & 3;
  float la[11];
#pragma unroll
  for (int u = 0; u < 11; u++) {
    int f = g + 4 * u;
    float acc = b_lab[f];
#pragma unroll
    for (int c4 = 0; c4 < 11; c4++) {
      float4 wv = *reinterpret_cast<const float4*>(&WlabT[f][4 * c4]);
      float4 lv = *reinterpret_cast<const float4*>(&lbl[e][4 * c4]);
      acc += wv.x*lv.x + wv.y*lv.y + wv.z*lv.z + wv.w*lv.w;
    }
    la[u] = acc >= 0.f ? acc : 0.2f * acc;
  }
  __syncthreads();             // all labels reads (incl. wexp) done
#pragma unroll
  for (int u = 0; u < 11; u++) lbl[e][g + 4 * u] = la[u];
  __syncthreads();             // lab ready

  {
    float4 labr[11];
#pragma unroll
    for (int c4 = 0; c4 < 11; c4++)
      labr[c4] = *reinterpret_cast<const float4*>(&lbl[e][4 * c4]);
    const float* P1r = P1e + (size_t)nbrL[e] * ME;
    float wex = wexpS[e];
#pragma unroll
    for (int rr = 0; rr < 3; rr++) {
      int r = g + 4 * rr;
      if (r < RK) {
        float tp = 0.f, tlp = 0.f;
#pragma unroll
        for (int c4 = 0; c4 < 11; c4++) {
          float4 p4 = *reinterpret_cast<const float4*>(P1r + r * FI + 4 * c4);
          float4 w4 = *reinterpret_cast<const float4*>(&WlT[r][4 * c4]);
          float4 l4 = labr[c4];
          tp  += l4.x*p4.x + l4.y*p4.y + l4.z*p4.z + l4.w*p4.w;
          tlp += l4.x*w4.x + l4.y*w4.y + l4.z*w4.z + l4.w*w4.w;
        }
        tfs[e][r] = (tp + P1r[484 + r]) * (tlp + blS[r]) * wex;
      }
    }
  }
  __syncthreads();

  const int nn = tid >> 6, lane = tid & 63;
  const int n = b * 4 + nn;
  if (lane < FI) {
    float acc2[RK];
#pragma unroll
    for (int r = 0; r < RK; r++) acc2[r] = 0.f;
    for (int k = 0; k < KNN; k++) {
      float lv = lbl[nn * 16 + k][lane];
#pragma unroll
      for (int r = 0; r < RK; r++) acc2[r] += lv * tfs[nn * 16 + k][r];
    }
#pragma unroll
    for (int r = 0; r < RK; r++) Ge[(size_t)n * ME + r * FI + lane] = acc2[r];
  } else if (lane < FI + RK) {
    int r = lane - FI;
    float ss = 0.f;
    for (int k = 0; k < KNN; k++) ss += tfs[nn * 16 + k][r];
    Ge[(size_t)n * ME + 484 + r] = ss;
  } else if (lane == 55) {
    Ge[(size_t)n * ME + 495] = 0.f;
  }
}

// ---------------- K5: out[n][fo] = sum_m Ge[n][m] * W2eTG[fo][m] — register-tiled ----------------
// 256 blocks; wave = 4 nodes (Ge reads broadcast); lane = fo row. No LDS.
__global__ __launch_bounds__(256) void k_out(const float* __restrict__ Ge,
                                             const float* __restrict__ W2eTG,
                                             float* __restrict__ out) {
  const int tid = threadIdx.x;
  const int grp = tid >> 6, lane = tid & 63;
  const int nb = blockIdx.x * 16 + grp * 4;
  const int foc = lane < FI ? lane : FI - 1;
  const float4* G4 = reinterpret_cast<const float4*>(Ge);
  const float4* W4 = reinterpret_cast<const float4*>(W2eTG);

  float a0 = 0.f, a1 = 0.f, a2 = 0.f, a3 = 0.f;
  for (int mc = 0; mc < ME / 4; mc++) {
    float4 w = W4[foc * (ME / 4) + mc];
    float4 g0 = G4[(size_t)(nb + 0) * (ME / 4) + mc];
    float4 g1 = G4[(size_t)(nb + 1) * (ME / 4) + mc];
    float4 g2 = G4[(size_t)(nb + 2) * (ME / 4) + mc];
    float4 g3 = G4[(size_t)(nb + 3) * (ME / 4) + mc];
    a0 += w.x*g0.x + w.y*g0.y + w.z*g0.z + w.w*g0.w;
    a1 += w.x*g1.x + w.y*g1.y + w.z*g1.z + w.w*g1.w;
    a2 += w.x*g2.x + w.y*g2.y + w.z*g2.z + w.w*g2.w;
    a3 += w.x*g3.x + w.y*g3.y + w.z*g3.z + w.w*g3.w;
  }
  if (lane < FI) {
    out[(size_t)(nb + 0) * FI + lane] = a0;
    out[(size_t)(nb + 1) * FI + lane] = a1;
    out[(size_t)(nb + 2) * FI + lane] = a2;
    out[(size_t)(nb + 3) * FI + lane] = a3;
  }
}

extern "C" void kernel_launch(void* const* d_in, const int* in_sizes, int n_in,
                              void* d_out, int out_size, void* d_ws, size_t ws_size,
                              hipStream_t stream) {
  const float* h     = (const float*)d_in[0];
  const float* mask  = (const float*)d_in[1];
  const float* W_lab = (const float*)d_in[2];
  const float* b_lab = (const float*)d_in[3];
  const float* W1    = (const float*)d_in[4];
  const float* b1    = (const float*)d_in[5];
  const float* W2    = (const float*)d_in[6];
  const float* b2    = (const float*)d_in[7];
  const float* Wl    = (const float*)d_in[8];
  const float* bl    = (const float*)d_in[9];

  float* sqw   = (float*)d_ws;                       // [4096]
  float* hT    = sqw + N;                            // [44*4096]
  int*   ctr   = (int*)(hT + (size_t)FI * N);        // [4096]
  int*   nbr   = ctr + N;                            // [65536]
  float* P1e   = (float*)(nbr + N * KNN);            // [4096*496]
  float* Ge    = P1e + (size_t)N * ME;               // [4096*496]
  float* WrG   = Ge + (size_t)N * ME;                // [496*44]
  float* W2eTG = WrG + 496 * FI;                     // [64*496]

  k_prep<<<N / 256, 256, 0, stream>>>(h, sqw, hT);
  k_wprep<<<64, 256, 0, stream>>>(W1, b1, W2, b2, WrG, W2eTG);
  k_dist_topk<<<N / NROW, 512, 0, stream>>>(hT, sqw, mask, ctr, nbr);
  k_P1<<<N / 16, 256, 0, stream>>>(h, WrG, P1e);
  k_edge<<<N * KNN / 64, 256, 0, stream>>>(h, ctr, nbr, W_lab, b_lab, Wl, bl, P1e, Ge);
  k_out<<<N / 16, 256, 0, stream>>>(Ge, W2eTG, (float*)d_out);
}